// Round 1
// baseline (2538.402 us; speedup 1.0000x reference)
//
#include <hip/hip_runtime.h>
#include <math.h>

#define LN_EPS 1e-5f

__device__ __forceinline__ float fast_tanh(float x) {
    // tanh(x) = (e^{2x}-1)/(e^{2x}+1), clamped to avoid inf/inf
    x = fminf(fmaxf(x, -15.0f), 15.0f);
    float e = __expf(2.0f * x);
    return (e - 1.0f) / (e + 1.0f);
}

// One FiLM dense path (t or s): h = LN(z_masked @ W + b); gamma/beta from e2;
// f = relu((1+gamma)*h + beta) @ oW + ob, returning only the two transform dims.
// ka = kept-dim row offset into W (0 or 2); pa = transform-dim col offset (0 or 2).
__device__ __forceinline__ void film_path(
    const float* __restrict__ Wl,  const float* __restrict__ bl,
    const float* __restrict__ lng, const float* __restrict__ lnb,
    const float* __restrict__ gWl, const float* __restrict__ gbl,
    const float* __restrict__ bWl, const float* __restrict__ bbl,
    const float* __restrict__ oWl, const float* __restrict__ obl,
    float za, float zb, int ka, int pa, const float e2[32],
    float& f0, float& f1)
{
    // h = z_masked @ W + b  (only 2 nonzero rows of W contribute)
    float h[32];
    #pragma unroll
    for (int j = 0; j < 32; ++j) {
        h[j] = fmaf(za, Wl[ka * 32 + j], fmaf(zb, Wl[(ka + 1) * 32 + j], bl[j]));
    }
    // LayerNorm over 32
    float m = 0.0f;
    #pragma unroll
    for (int j = 0; j < 32; ++j) m += h[j];
    m *= (1.0f / 32.0f);
    float v = 0.0f;
    #pragma unroll
    for (int j = 0; j < 32; ++j) { float d = h[j] - m; v = fmaf(d, d, v); }
    v *= (1.0f / 32.0f);
    float rstd = rsqrtf(v + LN_EPS);
    #pragma unroll
    for (int j = 0; j < 32; ++j) {
        h[j] = fmaf((h[j] - m) * rstd, lng[j], lnb[j]);
    }
    // gamma/beta matvecs (32x32 each), fused with FiLM + output projection.
    // j blocked by 4 so weight loads are contiguous 16B (s_load_dwordx4).
    f0 = obl[pa];
    f1 = obl[pa + 1];
    #pragma unroll
    for (int jb = 0; jb < 32; jb += 4) {
        float g[4], bt[4];
        #pragma unroll
        for (int q = 0; q < 4; ++q) { g[q] = gbl[jb + q]; bt[q] = bbl[jb + q]; }
        #pragma unroll
        for (int k = 0; k < 32; ++k) {
            float ek = e2[k];
            #pragma unroll
            for (int q = 0; q < 4; ++q) {
                g[q]  = fmaf(ek, gWl[k * 32 + jb + q], g[q]);
                bt[q] = fmaf(ek, bWl[k * 32 + jb + q], bt[q]);
            }
        }
        #pragma unroll
        for (int q = 0; q < 4; ++q) {
            float th = fmaxf(fmaf(1.0f + g[q], h[jb + q], bt[q]), 0.0f);
            f0 = fmaf(th, oWl[(jb + q) * 4 + pa], f0);
            f1 = fmaf(th, oWl[(jb + q) * 4 + pa + 1], f1);
        }
    }
}

__global__ __launch_bounds__(256) void realnvp_kernel(
    const float* __restrict__ x,    const float* __restrict__ y,
    const float* __restrict__ embW1, const float* __restrict__ embb1,
    const float* __restrict__ embW2, const float* __restrict__ embb2,
    const float* __restrict__ tW,   const float* __restrict__ tb,
    const float* __restrict__ t_ln_g, const float* __restrict__ t_ln_b,
    const float* __restrict__ t_gW, const float* __restrict__ t_gb,
    const float* __restrict__ t_bW, const float* __restrict__ t_bb,
    const float* __restrict__ toW,  const float* __restrict__ tob,
    const float* __restrict__ sW,   const float* __restrict__ sb,
    const float* __restrict__ s_ln_g, const float* __restrict__ s_ln_b,
    const float* __restrict__ s_gW, const float* __restrict__ s_gb,
    const float* __restrict__ s_bW, const float* __restrict__ s_bb,
    const float* __restrict__ soW,  const float* __restrict__ sob,
    float* __restrict__ out_z, float* __restrict__ out_ld, int B)
{
    int row = blockIdx.x * blockDim.x + threadIdx.x;
    if (row >= B) return;

    float4 xv = *reinterpret_cast<const float4*>(x + (size_t)row * 4);
    float4 yv4 = *reinterpret_cast<const float4*>(y + (size_t)row * 4);
    float z0 = xv.x, z1 = xv.y, z2 = xv.z, z3 = xv.w;
    float yv[4] = {yv4.x, yv4.y, yv4.z, yv4.w};
    float ld = 0.0f;

    #pragma unroll 1
    for (int i = 0; i < 8; ++i) {
        const int parity = i & 1;          // uniform across the wave
        const int ka = parity ? 2 : 0;     // kept dims (mask=1): rows of W used
        const int pa = parity ? 0 : 2;     // transform dims (rmask=1): cols of oW

        const float* W1  = embW1 + i * 4 * 32;
        const float* b1v = embb1 + i * 32;
        const float* W2  = embW2 + i * 32 * 32;
        const float* b2v = embb2 + i * 32;

        // ---- y_emb = relu(relu(y@W1+b1)@W2+b2) ----
        float e1[32];
        #pragma unroll
        for (int j = 0; j < 32; ++j) {
            float a = b1v[j];
            #pragma unroll
            for (int c = 0; c < 4; ++c) a = fmaf(yv[c], W1[c * 32 + j], a);
            e1[j] = fmaxf(a, 0.0f);
        }
        float e2[32];
        #pragma unroll
        for (int j = 0; j < 32; ++j) e2[j] = b2v[j];
        #pragma unroll
        for (int k = 0; k < 32; ++k) {
            float ek = e1[k];
            #pragma unroll
            for (int j = 0; j < 32; ++j) e2[j] = fmaf(ek, W2[k * 32 + j], e2[j]);
        }
        #pragma unroll
        for (int j = 0; j < 32; ++j) e2[j] = fmaxf(e2[j], 0.0f);

        // kept-dim z values (uniform selects)
        float za = parity ? z2 : z0;
        float zb = parity ? z3 : z1;

        // ---- t path ----
        float tf0, tf1;
        film_path(tW + i * 4 * 32, tb + i * 32,
                  t_ln_g + i * 32, t_ln_b + i * 32,
                  t_gW + i * 32 * 32, t_gb + i * 32,
                  t_bW + i * 32 * 32, t_bb + i * 32,
                  toW + i * 32 * 4, tob + i * 4,
                  za, zb, ka, pa, e2, tf0, tf1);

        // ---- s path ----
        float sf0, sf1;
        film_path(sW + i * 4 * 32, sb + i * 32,
                  s_ln_g + i * 32, s_ln_b + i * 32,
                  s_gW + i * 32 * 32, s_gb + i * 32,
                  s_bW + i * 32 * 32, s_bb + i * 32,
                  soW + i * 32 * 4, sob + i * 4,
                  za, zb, ka, pa, e2, sf0, sf1);

        sf0 = fast_tanh(sf0);
        sf1 = fast_tanh(sf1);
        float ex0 = __expf(sf0);
        float ex1 = __expf(sf1);

        if (parity) {
            z0 = fmaf(z0, ex0, tf0);
            z1 = fmaf(z1, ex1, tf1);
        } else {
            z2 = fmaf(z2, ex0, tf0);
            z3 = fmaf(z3, ex1, tf1);
        }
        ld += sf0 + sf1;
    }

    float4 zo = {z0, z1, z2, z3};
    *reinterpret_cast<float4*>(out_z + (size_t)row * 4) = zo;
    out_ld[row] = ld;
}

extern "C" void kernel_launch(void* const* d_in, const int* in_sizes, int n_in,
                              void* d_out, int out_size, void* d_ws, size_t ws_size,
                              hipStream_t stream) {
    const float* x      = (const float*)d_in[0];
    const float* y      = (const float*)d_in[1];
    const float* embW1  = (const float*)d_in[2];
    const float* embb1  = (const float*)d_in[3];
    const float* embW2  = (const float*)d_in[4];
    const float* embb2  = (const float*)d_in[5];
    const float* tW     = (const float*)d_in[6];
    const float* tb     = (const float*)d_in[7];
    const float* t_ln_g = (const float*)d_in[8];
    const float* t_ln_b = (const float*)d_in[9];
    const float* t_gW   = (const float*)d_in[10];
    const float* t_gb   = (const float*)d_in[11];
    const float* t_bW   = (const float*)d_in[12];
    const float* t_bb   = (const float*)d_in[13];
    const float* toW    = (const float*)d_in[14];
    const float* tob    = (const float*)d_in[15];
    const float* sW     = (const float*)d_in[16];
    const float* sb     = (const float*)d_in[17];
    const float* s_ln_g = (const float*)d_in[18];
    const float* s_ln_b = (const float*)d_in[19];
    const float* s_gW   = (const float*)d_in[20];
    const float* s_gb   = (const float*)d_in[21];
    const float* s_bW   = (const float*)d_in[22];
    const float* s_bb   = (const float*)d_in[23];
    const float* soW    = (const float*)d_in[24];
    const float* sob    = (const float*)d_in[25];

    int B = in_sizes[0] / 4;
    float* out_z  = (float*)d_out;
    float* out_ld = out_z + (size_t)B * 4;

    dim3 grid((B + 255) / 256), block(256);
    hipLaunchKernelGGL(realnvp_kernel, grid, block, 0, stream,
                       x, y, embW1, embb1, embW2, embb2,
                       tW, tb, t_ln_g, t_ln_b, t_gW, t_gb, t_bW, t_bb, toW, tob,
                       sW, sb, s_ln_g, s_ln_b, s_gW, s_gb, s_bW, s_bb, soW, sob,
                       out_z, out_ld, B);
}

// Round 2
// 477.182 us; speedup vs baseline: 5.3196x; 5.3196x over previous
//
#include <hip/hip_runtime.h>
#include <math.h>

#define LN_EPS 1e-5f
#define TPB 256

// ---------------- LDS layout (float offsets) ----------------
#define L_EMB_W1 0      // [4][32]
#define L_EMB_B1 128    // [32]
#define L_EMB_W2 160    // [32][32]
#define L_EMB_B2 1184   // [32]
#define PATH_BASE 1216
// per-path block:
#define P_W2R 0         // [2][32]  kept rows ka, ka+1 of W
#define P_B   64        // [32]
#define P_LNG 96        // [32]
#define P_LNB 128       // [32]
#define P_GW  160       // [32][32]
#define P_GB  1184      // [32]
#define P_BW  1216      // [32][32]
#define P_BB  2240      // [32]
#define P_OW2 2272      // [32][2]  only the 2 transform columns
#define P_OB2 2336      // [2]
#define PATH_SZ 2340    // padded, multiple of 4 (16B alignment)
#define LDS_FLOATS (PATH_BASE + 2 * PATH_SZ)   // 5896 floats = 23.6 KB

__device__ __forceinline__ float fast_tanh(float x) {
    x = fminf(fmaxf(x, -15.0f), 15.0f);
    float e = __expf(2.0f * x);
    return (e - 1.0f) / (e + 1.0f);
}

__global__ __launch_bounds__(TPB) void realnvp_kernel(
    const float* __restrict__ x,    const float* __restrict__ y,
    const float* __restrict__ embW1, const float* __restrict__ embb1,
    const float* __restrict__ embW2, const float* __restrict__ embb2,
    const float* __restrict__ tW,   const float* __restrict__ tb,
    const float* __restrict__ t_ln_g, const float* __restrict__ t_ln_b,
    const float* __restrict__ t_gW, const float* __restrict__ t_gb,
    const float* __restrict__ t_bW, const float* __restrict__ t_bb,
    const float* __restrict__ toW,  const float* __restrict__ tob,
    const float* __restrict__ sW,   const float* __restrict__ sb,
    const float* __restrict__ s_ln_g, const float* __restrict__ s_ln_b,
    const float* __restrict__ s_gW, const float* __restrict__ s_gb,
    const float* __restrict__ s_bW, const float* __restrict__ s_bb,
    const float* __restrict__ soW,  const float* __restrict__ sob,
    float* __restrict__ out_z, float* __restrict__ out_ld, int B)
{
    __shared__ __align__(16) float lds[LDS_FLOATS];
    const int tid = threadIdx.x;
    const int row = blockIdx.x * TPB + tid;   // B % TPB == 0

    float4 xv = *reinterpret_cast<const float4*>(x + (size_t)row * 4);
    float4 yv = *reinterpret_cast<const float4*>(y + (size_t)row * 4);
    float z0 = xv.x, z1 = xv.y, z2 = xv.z, z3 = xv.w;
    float ldet = 0.0f;

    #pragma unroll 1
    for (int i = 0; i < 8; ++i) {
        const int parity = i & 1;
        const int ka = parity ? 2 : 0;   // kept rows of W
        const int pa = parity ? 0 : 2;   // transform cols of oW

        // ---------------- stage this layer's weights into LDS ----------------
        __syncthreads();
        {
            // embW2: 1024 floats = 256 float4, exactly one per thread
            reinterpret_cast<float4*>(&lds[L_EMB_W2])[tid] =
                reinterpret_cast<const float4*>(embW2 + i * 1024)[tid];
            if (tid < 32) {  // embW1 128 floats = 32 float4
                reinterpret_cast<float4*>(&lds[L_EMB_W1])[tid] =
                    reinterpret_cast<const float4*>(embW1 + i * 128)[tid];
            } else if (tid < 64) {
                lds[L_EMB_B1 + tid - 32] = embb1[i * 32 + tid - 32];
            } else if (tid < 96) {
                lds[L_EMB_B2 + tid - 64] = embb2[i * 32 + tid - 64];
            }
            #pragma unroll 1
            for (int p = 0; p < 2; ++p) {
                float* d = &lds[PATH_BASE + p * PATH_SZ];
                const float* Wsrc = (p ? sW : tW) + i * 128;
                const float* bsrc = (p ? sb : tb) + i * 32;
                const float* lgsrc = (p ? s_ln_g : t_ln_g) + i * 32;
                const float* lbsrc = (p ? s_ln_b : t_ln_b) + i * 32;
                const float* gwsrc = (p ? s_gW : t_gW) + i * 1024;
                const float* gbsrc = (p ? s_gb : t_gb) + i * 32;
                const float* bwsrc = (p ? s_bW : t_bW) + i * 1024;
                const float* bbsrc = (p ? s_bb : t_bb) + i * 32;
                const float* owsrc = (p ? soW : toW) + i * 128;
                const float* obsrc = (p ? sob : tob) + i * 4;

                reinterpret_cast<float4*>(&d[P_GW])[tid] =
                    reinterpret_cast<const float4*>(gwsrc)[tid];
                reinterpret_cast<float4*>(&d[P_BW])[tid] =
                    reinterpret_cast<const float4*>(bwsrc)[tid];
                if (tid < 64) {          // W kept rows: [r][j] = W[(ka+r)*32 + j]
                    d[P_W2R + tid] = Wsrc[(ka + (tid >> 5)) * 32 + (tid & 31)];
                } else if (tid < 96) {
                    d[P_B + tid - 64] = bsrc[tid - 64];
                } else if (tid < 128) {
                    d[P_LNG + tid - 96] = lgsrc[tid - 96];
                } else if (tid < 160) {
                    d[P_LNB + tid - 128] = lbsrc[tid - 128];
                } else if (tid < 192) {
                    d[P_GB + tid - 160] = gbsrc[tid - 160];
                } else if (tid < 224) {
                    d[P_BB + tid - 192] = bbsrc[tid - 192];
                } else {                 // 224..255: oW 2 live columns (64 floats)
                    int t = (tid - 224) * 2;
                    d[P_OW2 + t]     = owsrc[(t >> 1) * 4 + pa + 0 * 0 + ((t) & 1)];
                    d[P_OW2 + t + 1] = owsrc[((t + 1) >> 1) * 4 + pa + ((t + 1) & 1)];
                }
                if (tid < 2) d[P_OB2 + tid] = obsrc[pa + tid];
            }
        }
        __syncthreads();

        // ---------------- e1 = relu(y @ W1 + b1) ----------------
        float e1[32];
        #pragma unroll
        for (int jb = 0; jb < 8; ++jb) {
            float4 bv = *reinterpret_cast<const float4*>(&lds[L_EMB_B1 + jb * 4]);
            float4 w0 = *reinterpret_cast<const float4*>(&lds[L_EMB_W1 + 0 * 32 + jb * 4]);
            float4 w1 = *reinterpret_cast<const float4*>(&lds[L_EMB_W1 + 1 * 32 + jb * 4]);
            float4 w2 = *reinterpret_cast<const float4*>(&lds[L_EMB_W1 + 2 * 32 + jb * 4]);
            float4 w3 = *reinterpret_cast<const float4*>(&lds[L_EMB_W1 + 3 * 32 + jb * 4]);
            e1[jb*4+0] = fmaxf(fmaf(yv.x,w0.x,fmaf(yv.y,w1.x,fmaf(yv.z,w2.x,fmaf(yv.w,w3.x,bv.x)))), 0.f);
            e1[jb*4+1] = fmaxf(fmaf(yv.x,w0.y,fmaf(yv.y,w1.y,fmaf(yv.z,w2.y,fmaf(yv.w,w3.y,bv.y)))), 0.f);
            e1[jb*4+2] = fmaxf(fmaf(yv.x,w0.z,fmaf(yv.y,w1.z,fmaf(yv.z,w2.z,fmaf(yv.w,w3.z,bv.z)))), 0.f);
            e1[jb*4+3] = fmaxf(fmaf(yv.x,w0.w,fmaf(yv.y,w1.w,fmaf(yv.z,w2.w,fmaf(yv.w,w3.w,bv.w)))), 0.f);
        }

        // ---------------- e2 = relu(e1 @ W2 + b2) ----------------
        float e2[32];
        #pragma unroll
        for (int jb = 0; jb < 8; ++jb) {
            float4 acc = *reinterpret_cast<const float4*>(&lds[L_EMB_B2 + jb * 4]);
            #pragma unroll
            for (int k = 0; k < 32; ++k) {
                float4 w = *reinterpret_cast<const float4*>(&lds[L_EMB_W2 + k * 32 + jb * 4]);
                acc.x = fmaf(e1[k], w.x, acc.x);
                acc.y = fmaf(e1[k], w.y, acc.y);
                acc.z = fmaf(e1[k], w.z, acc.z);
                acc.w = fmaf(e1[k], w.w, acc.w);
            }
            e2[jb*4+0] = fmaxf(acc.x, 0.f);
            e2[jb*4+1] = fmaxf(acc.y, 0.f);
            e2[jb*4+2] = fmaxf(acc.z, 0.f);
            e2[jb*4+3] = fmaxf(acc.w, 0.f);
        }

        const float za = parity ? z2 : z0;
        const float zb = parity ? z3 : z1;

        // ---------------- t and s FiLM paths ----------------
        float tf0 = 0.f, tf1 = 0.f, sf0 = 0.f, sf1 = 0.f;
        #pragma unroll 1
        for (int p = 0; p < 2; ++p) {
            const float* pb = &lds[PATH_BASE + p * PATH_SZ];

            // pass 1: LN statistics of h (h recomputed in pass 2)
            float sum = 0.f, ssq = 0.f;
            #pragma unroll 1
            for (int jb = 0; jb < 8; ++jb) {
                float4 wa = *reinterpret_cast<const float4*>(&pb[P_W2R + jb * 4]);
                float4 wb = *reinterpret_cast<const float4*>(&pb[P_W2R + 32 + jb * 4]);
                float4 bv = *reinterpret_cast<const float4*>(&pb[P_B + jb * 4]);
                float h0 = fmaf(za, wa.x, fmaf(zb, wb.x, bv.x));
                float h1 = fmaf(za, wa.y, fmaf(zb, wb.y, bv.y));
                float h2 = fmaf(za, wa.z, fmaf(zb, wb.z, bv.z));
                float h3 = fmaf(za, wa.w, fmaf(zb, wb.w, bv.w));
                sum += (h0 + h1) + (h2 + h3);
                ssq = fmaf(h0, h0, ssq); ssq = fmaf(h1, h1, ssq);
                ssq = fmaf(h2, h2, ssq); ssq = fmaf(h3, h3, ssq);
            }
            float m = sum * (1.f / 32.f);
            float var = ssq * (1.f / 32.f) - m * m;
            float rstd = rsqrtf(var + LN_EPS);

            float f0 = pb[P_OB2 + 0], f1 = pb[P_OB2 + 1];
            #pragma unroll 1
            for (int jb = 0; jb < 8; ++jb) {
                float4 wa = *reinterpret_cast<const float4*>(&pb[P_W2R + jb * 4]);
                float4 wb = *reinterpret_cast<const float4*>(&pb[P_W2R + 32 + jb * 4]);
                float4 bv = *reinterpret_cast<const float4*>(&pb[P_B + jb * 4]);
                float h0 = fmaf(za, wa.x, fmaf(zb, wb.x, bv.x));
                float h1 = fmaf(za, wa.y, fmaf(zb, wb.y, bv.y));
                float h2 = fmaf(za, wa.z, fmaf(zb, wb.z, bv.z));
                float h3 = fmaf(za, wa.w, fmaf(zb, wb.w, bv.w));
                float4 lg = *reinterpret_cast<const float4*>(&pb[P_LNG + jb * 4]);
                float4 lb = *reinterpret_cast<const float4*>(&pb[P_LNB + jb * 4]);
                float n0 = fmaf((h0 - m) * rstd, lg.x, lb.x);
                float n1 = fmaf((h1 - m) * rstd, lg.y, lb.y);
                float n2 = fmaf((h2 - m) * rstd, lg.z, lb.z);
                float n3 = fmaf((h3 - m) * rstd, lg.w, lb.w);

                float4 g  = *reinterpret_cast<const float4*>(&pb[P_GB + jb * 4]);
                float4 bt = *reinterpret_cast<const float4*>(&pb[P_BB + jb * 4]);
                #pragma unroll
                for (int k = 0; k < 32; ++k) {
                    float4 wg = *reinterpret_cast<const float4*>(&pb[P_GW + k * 32 + jb * 4]);
                    float4 wb2 = *reinterpret_cast<const float4*>(&pb[P_BW + k * 32 + jb * 4]);
                    float ek = e2[k];
                    g.x = fmaf(ek, wg.x, g.x);   g.y = fmaf(ek, wg.y, g.y);
                    g.z = fmaf(ek, wg.z, g.z);   g.w = fmaf(ek, wg.w, g.w);
                    bt.x = fmaf(ek, wb2.x, bt.x); bt.y = fmaf(ek, wb2.y, bt.y);
                    bt.z = fmaf(ek, wb2.z, bt.z); bt.w = fmaf(ek, wb2.w, bt.w);
                }
                // relu((1+g)*n + bt) = relu(n + g*n + bt), then project
                float th0 = fmaxf(fmaf(g.x, n0, n0 + bt.x), 0.f);
                float th1 = fmaxf(fmaf(g.y, n1, n1 + bt.y), 0.f);
                float th2 = fmaxf(fmaf(g.z, n2, n2 + bt.z), 0.f);
                float th3 = fmaxf(fmaf(g.w, n3, n3 + bt.w), 0.f);
                float2 o0 = *reinterpret_cast<const float2*>(&pb[P_OW2 + (jb * 4 + 0) * 2]);
                float2 o1 = *reinterpret_cast<const float2*>(&pb[P_OW2 + (jb * 4 + 1) * 2]);
                float2 o2 = *reinterpret_cast<const float2*>(&pb[P_OW2 + (jb * 4 + 2) * 2]);
                float2 o3 = *reinterpret_cast<const float2*>(&pb[P_OW2 + (jb * 4 + 3) * 2]);
                f0 = fmaf(th0, o0.x, f0); f1 = fmaf(th0, o0.y, f1);
                f0 = fmaf(th1, o1.x, f0); f1 = fmaf(th1, o1.y, f1);
                f0 = fmaf(th2, o2.x, f0); f1 = fmaf(th2, o2.y, f1);
                f0 = fmaf(th3, o3.x, f0); f1 = fmaf(th3, o3.y, f1);
            }
            if (p == 0) { tf0 = f0; tf1 = f1; }
            else        { sf0 = f0; sf1 = f1; }
        }

        sf0 = fast_tanh(sf0);
        sf1 = fast_tanh(sf1);
        float ex0 = __expf(sf0);
        float ex1 = __expf(sf1);
        if (parity) {
            z0 = fmaf(z0, ex0, tf0);
            z1 = fmaf(z1, ex1, tf1);
        } else {
            z2 = fmaf(z2, ex0, tf0);
            z3 = fmaf(z3, ex1, tf1);
        }
        ldet += sf0 + sf1;
    }

    float4 zo = {z0, z1, z2, z3};
    *reinterpret_cast<float4*>(out_z + (size_t)row * 4) = zo;
    out_ld[row] = ldet;
}

extern "C" void kernel_launch(void* const* d_in, const int* in_sizes, int n_in,
                              void* d_out, int out_size, void* d_ws, size_t ws_size,
                              hipStream_t stream) {
    const float* x      = (const float*)d_in[0];
    const float* y      = (const float*)d_in[1];
    const float* embW1  = (const float*)d_in[2];
    const float* embb1  = (const float*)d_in[3];
    const float* embW2  = (const float*)d_in[4];
    const float* embb2  = (const float*)d_in[5];
    const float* tW     = (const float*)d_in[6];
    const float* tb     = (const float*)d_in[7];
    const float* t_ln_g = (const float*)d_in[8];
    const float* t_ln_b = (const float*)d_in[9];
    const float* t_gW   = (const float*)d_in[10];
    const float* t_gb   = (const float*)d_in[11];
    const float* t_bW   = (const float*)d_in[12];
    const float* t_bb   = (const float*)d_in[13];
    const float* toW    = (const float*)d_in[14];
    const float* tob    = (const float*)d_in[15];
    const float* sW     = (const float*)d_in[16];
    const float* sb     = (const float*)d_in[17];
    const float* s_ln_g = (const float*)d_in[18];
    const float* s_ln_b = (const float*)d_in[19];
    const float* s_gW   = (const float*)d_in[20];
    const float* s_gb   = (const float*)d_in[21];
    const float* s_bW   = (const float*)d_in[22];
    const float* s_bb   = (const float*)d_in[23];
    const float* soW    = (const float*)d_in[24];
    const float* sob    = (const float*)d_in[25];

    int B = in_sizes[0] / 4;
    float* out_z  = (float*)d_out;
    float* out_ld = out_z + (size_t)B * 4;

    dim3 grid(B / TPB), block(TPB);
    hipLaunchKernelGGL(realnvp_kernel, grid, block, 0, stream,
                       x, y, embW1, embb1, embW2, embb2,
                       tW, tb, t_ln_g, t_ln_b, t_gW, t_gb, t_bW, t_bb, toW, tob,
                       sW, sb, s_ln_g, s_ln_b, s_gW, s_gb, s_bW, s_bb, soW, sob,
                       out_z, out_ld, B);
}

// Round 3
// 203.529 us; speedup vs baseline: 12.4720x; 2.3445x over previous
//
#include <hip/hip_runtime.h>
#include <math.h>

#define LN_EPS 1e-5f
typedef float f4 __attribute__((ext_vector_type(4)));
typedef float f2 __attribute__((ext_vector_type(2)));
typedef short bf16x8 __attribute__((ext_vector_type(8)));

__device__ __forceinline__ unsigned short rne_bf16(float f) {
    unsigned u = __builtin_bit_cast(unsigned, f);
    unsigned r = (u + 0x7FFFu + ((u >> 16) & 1u)) >> 16;
    return (unsigned short)r;
}

__device__ __forceinline__ float fast_tanh(float x) {
    x = fminf(fmaxf(x, -15.0f), 15.0f);
    float e = __expf(2.0f * x);
    return (e - 1.0f) / (e + 1.0f);
}

template <int CTRL>
__device__ __forceinline__ float dpp_add_step(float v) {
    int t = __builtin_amdgcn_update_dpp(0, __builtin_bit_cast(int, v), CTRL, 0xf, 0xf, true);
    return v + __builtin_bit_cast(float, t);
}
// sum across the 16-lane DPP row (our lane-group); result identical in all 16 lanes
__device__ __forceinline__ float reduce16(float v) {
    v = dpp_add_step<0xB1>(v);   // quad_perm(1,0,3,2)
    v = dpp_add_step<0x4E>(v);   // quad_perm(2,3,0,1)
    v = dpp_add_step<0x141>(v);  // row_half_mirror
    v = dpp_add_step<0x140>(v);  // row_mirror
    return v;
}

// ws16 frag layout: [layer][mat(5)][hilo(2)][half(2)][lane(64)][j(8)] bf16
#define FRAGLD(i, m, hl, hf) \
    (*(const bf16x8*)(ws16 + (size_t)(((i)*5 + (m))*2048 + (hl)*1024 + (hf)*512 + lane*8)))

// ---------------- preprocessing: weights -> MFMA B-fragments (hi/lo bf16) ----------------
__global__ void preproc_kernel(
    const float* __restrict__ embW2,
    const float* __restrict__ t_gW, const float* __restrict__ t_bW,
    const float* __restrict__ s_gW, const float* __restrict__ s_bW,
    const float* __restrict__ tW, const float* __restrict__ tb,
    const float* __restrict__ sW, const float* __restrict__ sb,
    unsigned short* __restrict__ ws16, float* __restrict__ wsLN)
{
    const int i = blockIdx.x;           // layer
    const int tid = threadIdx.x;
    const float* mats[5] = {embW2 + i * 1024, t_gW + i * 1024, t_bW + i * 1024,
                            s_gW + i * 1024, s_bW + i * 1024};
    for (int m = 0; m < 5; ++m) {
        const float* src = mats[m];
        const bool perm = (m > 0);      // gamma/beta GEMMs consume k-interleaved e2
        for (int e = tid; e < 1024; e += 256) {
            int half = e >> 9, ln = (e >> 3) & 63, j = e & 7;
            int p = (ln >> 4) * 8 + j;
            int k = perm ? ((p >> 1) | ((p & 1) << 4)) : p;
            int c = half * 16 + (ln & 15);
            float w = src[k * 32 + c];
            unsigned short hi = rne_bf16(w);
            float whi = __builtin_bit_cast(float, (unsigned)hi << 16);
            unsigned short lo = rne_bf16(w - whi);
            size_t base = (size_t)(i * 5 + m) * 2048;
            ws16[base + e] = hi;
            ws16[base + 1024 + e] = lo;
        }
    }
    // analytic-LN weight sums: h = za*w0 + zb*w1 + b over 32 cols
    if (tid < 2) {
        int p = tid;
        const float* W = (p ? sW : tW) + i * 128;
        const float* b = (p ? sb : tb) + i * 32;
        int ka = (i & 1) ? 2 : 0;
        float S0 = 0, S1 = 0, Sb = 0, Q00 = 0, Q11 = 0, Qbb = 0, Q01 = 0, Q0b = 0, Q1b = 0;
        for (int c = 0; c < 32; ++c) {
            float w0 = W[ka * 32 + c], w1 = W[(ka + 1) * 32 + c], bc = b[c];
            S0 += w0; S1 += w1; Sb += bc;
            Q00 += w0 * w0; Q11 += w1 * w1; Qbb += bc * bc;
            Q01 += w0 * w1; Q0b += w0 * bc; Q1b += w1 * bc;
        }
        float* o = wsLN + (i * 2 + p) * 16;
        o[0] = S0; o[1] = S1; o[2] = Sb; o[3] = Q00; o[4] = Q11;
        o[5] = Qbb; o[6] = Q01; o[7] = Q0b; o[8] = Q1b;
    }
}

// ---------------- one FiLM path (t or s) on the matrix cores ----------------
__device__ __forceinline__ void film_path(
    const unsigned short* __restrict__ ws16, int i, int matg, int matb,
    const float* __restrict__ Wsrc, const float* __restrict__ bsrc,
    const float* __restrict__ lngsrc, const float* __restrict__ lnbsrc,
    const float* __restrict__ gbsrc, const float* __restrict__ bbsrc,
    const float* __restrict__ oWsrc, const float* __restrict__ obsrc,
    const float* __restrict__ lnS, int parity, int ka, int pa, int lane,
    const bf16x8* a2, const f4 (*zr)[4], f4* f0o, f4* f1o)
{
    const int r = lane & 15;
    bf16x8 gh0 = FRAGLD(i, matg, 0, 0), gh1 = FRAGLD(i, matg, 0, 1);
    bf16x8 gl0 = FRAGLD(i, matg, 1, 0), gl1 = FRAGLD(i, matg, 1, 1);
    bf16x8 bh0 = FRAGLD(i, matb, 0, 0), bh1 = FRAGLD(i, matb, 0, 1);
    bf16x8 bl0 = FRAGLD(i, matb, 1, 0), bl1 = FRAGLD(i, matb, 1, 1);

    f4 gacc[2][2], bacc[2][2];
    const f4 zero4 = {0.f, 0.f, 0.f, 0.f};
    #pragma unroll
    for (int t = 0; t < 2; ++t) {
        gacc[t][0] = __builtin_amdgcn_mfma_f32_16x16x32_bf16(a2[t], gh0, zero4, 0, 0, 0);
        gacc[t][0] = __builtin_amdgcn_mfma_f32_16x16x32_bf16(a2[t], gl0, gacc[t][0], 0, 0, 0);
        gacc[t][1] = __builtin_amdgcn_mfma_f32_16x16x32_bf16(a2[t], gh1, zero4, 0, 0, 0);
        gacc[t][1] = __builtin_amdgcn_mfma_f32_16x16x32_bf16(a2[t], gl1, gacc[t][1], 0, 0, 0);
        bacc[t][0] = __builtin_amdgcn_mfma_f32_16x16x32_bf16(a2[t], bh0, zero4, 0, 0, 0);
        bacc[t][0] = __builtin_amdgcn_mfma_f32_16x16x32_bf16(a2[t], bl0, bacc[t][0], 0, 0, 0);
        bacc[t][1] = __builtin_amdgcn_mfma_f32_16x16x32_bf16(a2[t], bh1, zero4, 0, 0, 0);
        bacc[t][1] = __builtin_amdgcn_mfma_f32_16x16x32_bf16(a2[t], bl1, bacc[t][1], 0, 0, 0);
    }

    // per-lane params (col c = r for half0, r+16 for half1)
    float wk0l = Wsrc[ka * 32 + r],        wk0h = Wsrc[ka * 32 + 16 + r];
    float wk1l = Wsrc[(ka + 1) * 32 + r],  wk1h = Wsrc[(ka + 1) * 32 + 16 + r];
    float bl_ = bsrc[r], bh_ = bsrc[r + 16];
    float lngl = lngsrc[r], lngh = lngsrc[r + 16];
    float lnbl = lnbsrc[r], lnbh = lnbsrc[r + 16];
    float gbl = gbsrc[r], gbh = gbsrc[r + 16];
    float bbl = bbsrc[r], bbh = bbsrc[r + 16];
    f2 owl = *(const f2*)(oWsrc + r * 4 + pa);
    f2 owh = *(const f2*)(oWsrc + (r + 16) * 4 + pa);
    float ob0 = obsrc[pa], ob1 = obsrc[pa + 1];
    float S0 = lnS[0], S1 = lnS[1], Sb = lnS[2], Q00 = lnS[3], Q11 = lnS[4];
    float Qbb = lnS[5], Q01 = lnS[6], Q0b = lnS[7], Q1b = lnS[8];

    #pragma unroll
    for (int t = 0; t < 2; ++t) {
        #pragma unroll
        for (int q = 0; q < 4; ++q) {
            f4 zq = zr[t][q];
            float za = parity ? zq[2] : zq[0];
            float zb = parity ? zq[3] : zq[1];
            // analytic LN stats
            float m = fmaf(za, S0, fmaf(zb, S1, Sb)) * 0.03125f;
            float ex2 = fmaf(za * za, Q00,
                        fmaf(zb * zb, Q11,
                        fmaf(2.0f * za * zb, Q01,
                        fmaf(2.0f * za, Q0b,
                        fmaf(2.0f * zb, Q1b, Qbb))))) * 0.03125f;
            float rstd = rsqrtf(fmaxf(ex2 - m * m, 0.0f) + LN_EPS);
            float hl = fmaf(za, wk0l, fmaf(zb, wk1l, bl_));
            float hh = fmaf(za, wk0h, fmaf(zb, wk1h, bh_));
            float nl = fmaf((hl - m) * rstd, lngl, lnbl);
            float nh = fmaf((hh - m) * rstd, lngh, lnbh);
            float gl = gacc[t][0][q] + gbl, gh = gacc[t][1][q] + gbh;
            float btl = bacc[t][0][q] + bbl, bth = bacc[t][1][q] + bbh;
            float thl = fmaxf(fmaf(gl, nl, nl + btl), 0.f);
            float thh = fmaxf(fmaf(gh, nh, nh + bth), 0.f);
            float p0 = fmaf(thl, owl[0], thh * owh[0]);
            float p1 = fmaf(thl, owl[1], thh * owh[1]);
            p0 = reduce16(p0);
            p1 = reduce16(p1);
            f0o[t][q] = p0 + ob0;
            f1o[t][q] = p1 + ob1;
        }
    }
}

__global__ __launch_bounds__(256) void realnvp_mfma(
    const float* __restrict__ x, const float* __restrict__ y,
    const float* __restrict__ embW1, const float* __restrict__ embb1,
    const float* __restrict__ embb2,
    const float* __restrict__ tW, const float* __restrict__ tb,
    const float* __restrict__ t_ln_g, const float* __restrict__ t_ln_b,
    const float* __restrict__ t_gb, const float* __restrict__ t_bb,
    const float* __restrict__ toW, const float* __restrict__ tob,
    const float* __restrict__ sW, const float* __restrict__ sb,
    const float* __restrict__ s_ln_g, const float* __restrict__ s_ln_b,
    const float* __restrict__ s_gb, const float* __restrict__ s_bb,
    const float* __restrict__ soW, const float* __restrict__ sob,
    const unsigned short* __restrict__ ws16, const float* __restrict__ wsLN,
    float* __restrict__ out_z, float* __restrict__ out_ld)
{
    __shared__ __align__(16) unsigned char ldsbuf[4 * 2560];
    const int lane = threadIdx.x & 63;
    const int wv = threadIdx.x >> 6;
    const int r = lane & 15, g = lane >> 4;
    unsigned char* T = ldsbuf + wv * 2560;       // 32 rows x 80B pitch
    const int row0 = (blockIdx.x * 4 + wv) * 32;

    // z in registers: zr[t][q] = z row (row0 + 16t + 4g + q), identical across the 16-lane group
    f4 zr[2][4];
    #pragma unroll
    for (int t = 0; t < 2; ++t)
        #pragma unroll
        for (int q = 0; q < 4; ++q)
            zr[t][q] = *(const f4*)(x + (size_t)(row0 + 16 * t + 4 * g + q) * 4);
    f4 ld0 = {0.f, 0.f, 0.f, 0.f}, ld1 = {0.f, 0.f, 0.f, 0.f};

    #pragma unroll 1
    for (int i = 0; i < 8; ++i) {
        const int parity = i & 1;
        const int ka = parity ? 2 : 0, pa = parity ? 0 : 2;

        // ---- e1 in A-fragment layout (row = r, k-slice = g*8..g*8+7) ----
        const float* W1 = embW1 + i * 128;
        f4 w1a[4], w1b[4];
        #pragma unroll
        for (int c = 0; c < 4; ++c) {
            w1a[c] = *(const f4*)(W1 + c * 32 + g * 8);
            w1b[c] = *(const f4*)(W1 + c * 32 + g * 8 + 4);
        }
        f4 b1a = *(const f4*)(embb1 + i * 32 + g * 8);
        f4 b1b = *(const f4*)(embb1 + i * 32 + g * 8 + 4);
        bf16x8 w2h0 = FRAGLD(i, 0, 0, 0), w2h1 = FRAGLD(i, 0, 0, 1);
        bf16x8 w2l0 = FRAGLD(i, 0, 1, 0), w2l1 = FRAGLD(i, 0, 1, 1);

        bf16x8 a1[2];
        #pragma unroll
        for (int t = 0; t < 2; ++t) {
            f4 y4 = *(const f4*)(y + (size_t)(row0 + 16 * t + r) * 4);
            #pragma unroll
            for (int j = 0; j < 8; ++j) {
                float acc = (j < 4) ? b1a[j & 3] : b1b[j & 3];
                #pragma unroll
                for (int c = 0; c < 4; ++c)
                    acc = fmaf(y4[c], (j < 4) ? w1a[c][j & 3] : w1b[c][j & 3], acc);
                a1[t][j] = (short)rne_bf16(fmaxf(acc, 0.f));
            }
        }

        // ---- e2 = relu(e1 @ W2 + b2) via MFMA (hi+lo weights) ----
        const f4 zero4 = {0.f, 0.f, 0.f, 0.f};
        f4 e2a[2][2];
        #pragma unroll
        for (int t = 0; t < 2; ++t) {
            e2a[t][0] = __builtin_amdgcn_mfma_f32_16x16x32_bf16(a1[t], w2h0, zero4, 0, 0, 0);
            e2a[t][0] = __builtin_amdgcn_mfma_f32_16x16x32_bf16(a1[t], w2l0, e2a[t][0], 0, 0, 0);
            e2a[t][1] = __builtin_amdgcn_mfma_f32_16x16x32_bf16(a1[t], w2h1, zero4, 0, 0, 0);
            e2a[t][1] = __builtin_amdgcn_mfma_f32_16x16x32_bf16(a1[t], w2l1, e2a[t][1], 0, 0, 0);
        }
        float b2l = embb2[i * 32 + r], b2h = embb2[i * 32 + r + 16];

        // ---- D-layout -> A-layout transpose through LDS (k-interleaved pack) ----
        #pragma unroll
        for (int t = 0; t < 2; ++t)
            #pragma unroll
            for (int q = 0; q < 4; ++q) {
                float vl = fmaxf(e2a[t][0][q] + b2l, 0.f);
                float vh = fmaxf(e2a[t][1][q] + b2h, 0.f);
                unsigned w = (unsigned)rne_bf16(vl) | ((unsigned)rne_bf16(vh) << 16);
                *(unsigned*)(T + (16 * t + 4 * g + q) * 80 + r * 4) = w;
            }
        asm volatile("s_waitcnt lgkmcnt(0)" ::: "memory");
        __builtin_amdgcn_sched_barrier(0);
        bf16x8 a2[2];
        #pragma unroll
        for (int t = 0; t < 2; ++t)
            a2[t] = *(const bf16x8*)(T + (16 * t + r) * 80 + g * 16);

        // ---- t and s FiLM paths ----
        f4 tf0[2], tf1[2], sf0[2], sf1[2];
        film_path(ws16, i, 1, 2, tW + i * 128, tb + i * 32,
                  t_ln_g + i * 32, t_ln_b + i * 32, t_gb + i * 32, t_bb + i * 32,
                  toW + i * 128, tob + i * 4, wsLN + (i * 2 + 0) * 16,
                  parity, ka, pa, lane, a2, zr, tf0, tf1);
        film_path(ws16, i, 3, 4, sW + i * 128, sb + i * 32,
                  s_ln_g + i * 32, s_ln_b + i * 32, s_gb + i * 32, s_bb + i * 32,
                  soW + i * 128, sob + i * 4, wsLN + (i * 2 + 1) * 16,
                  parity, ka, pa, lane, a2, zr, sf0, sf1);

        // ---- coupling update ----
        #pragma unroll
        for (int t = 0; t < 2; ++t)
            #pragma unroll
            for (int q = 0; q < 4; ++q) {
                float s0 = fast_tanh(sf0[t][q]);
                float s1 = fast_tanh(sf1[t][q]);
                float eA = __expf(s0), eB = __expf(s1);
                float t0 = tf0[t][q], t1 = tf1[t][q];
                f4 zq = zr[t][q];
                zq[0] = parity ? fmaf(zq[0], eA, t0) : zq[0];
                zq[1] = parity ? fmaf(zq[1], eB, t1) : zq[1];
                zq[2] = parity ? zq[2] : fmaf(zq[2], eA, t0);
                zq[3] = parity ? zq[3] : fmaf(zq[3], eB, t1);
                zr[t][q] = zq;
                if (t == 0) ld0[q] += s0 + s1; else ld1[q] += s0 + s1;
            }
    }

    // ---- outputs (one writer lane per group) ----
    if (r == 0) {
        #pragma unroll
        for (int t = 0; t < 2; ++t)
            #pragma unroll
            for (int q = 0; q < 4; ++q)
                *(f4*)(out_z + (size_t)(row0 + 16 * t + 4 * g + q) * 4) = zr[t][q];
        *(f4*)(out_ld + row0 + g * 4) = ld0;
        *(f4*)(out_ld + row0 + 16 + g * 4) = ld1;
    }
}

extern "C" void kernel_launch(void* const* d_in, const int* in_sizes, int n_in,
                              void* d_out, int out_size, void* d_ws, size_t ws_size,
                              hipStream_t stream) {
    const float* x      = (const float*)d_in[0];
    const float* y      = (const float*)d_in[1];
    const float* embW1  = (const float*)d_in[2];
    const float* embb1  = (const float*)d_in[3];
    const float* embW2  = (const float*)d_in[4];
    const float* embb2  = (const float*)d_in[5];
    const float* tW     = (const float*)d_in[6];
    const float* tb     = (const float*)d_in[7];
    const float* t_ln_g = (const float*)d_in[8];
    const float* t_ln_b = (const float*)d_in[9];
    const float* t_gW   = (const float*)d_in[10];
    const float* t_gb   = (const float*)d_in[11];
    const float* t_bW   = (const float*)d_in[12];
    const float* t_bb   = (const float*)d_in[13];
    const float* toW    = (const float*)d_in[14];
    const float* tob    = (const float*)d_in[15];
    const float* sW     = (const float*)d_in[16];
    const float* sb     = (const float*)d_in[17];
    const float* s_ln_g = (const float*)d_in[18];
    const float* s_ln_b = (const float*)d_in[19];
    const float* s_gW   = (const float*)d_in[20];
    const float* s_gb   = (const float*)d_in[21];
    const float* s_bW   = (const float*)d_in[22];
    const float* s_bb   = (const float*)d_in[23];
    const float* soW    = (const float*)d_in[24];
    const float* sob    = (const float*)d_in[25];

    if (ws_size < 164864) return;  // 160KB frags + 1KB LN sums
    unsigned short* ws16 = (unsigned short*)d_ws;
    float* wsLN = (float*)((char*)d_ws + 163840);

    int B = in_sizes[0] / 4;
    float* out_z  = (float*)d_out;
    float* out_ld = out_z + (size_t)B * 4;

    hipLaunchKernelGGL(preproc_kernel, dim3(8), dim3(256), 0, stream,
                       embW2, t_gW, t_bW, s_gW, s_bW, tW, tb, sW, sb, ws16, wsLN);
    hipLaunchKernelGGL(realnvp_mfma, dim3(B / 128), dim3(256), 0, stream,
                       x, y, embW1, embb1, embb2,
                       tW, tb, t_ln_g, t_ln_b, t_gb, t_bb, toW, tob,
                       sW, sb, s_ln_g, s_ln_b, s_gb, s_bb, soW, sob,
                       ws16, wsLN, out_z, out_ld);
}

// Round 4
// 145.175 us; speedup vs baseline: 17.4851x; 1.4020x over previous
//
#include <hip/hip_runtime.h>
#include <math.h>

#define LN_EPS 1e-5f
#define LOG2E 1.44269504088896f

typedef float f4 __attribute__((ext_vector_type(4)));
typedef float f2 __attribute__((ext_vector_type(2)));
typedef short bf16x8 __attribute__((ext_vector_type(8)));

// d_ws layout (bytes):
//   [0, 98304)        frags: [layer8][slot6][half2][lane64][j8] bf16
//                     slots: 0=W2hi 1=W2lo 2=tG 3=tB 4=sG 5=sB
//   [98304, 139264)   params: [layer8][path2][vec5][r16][4] f32
//   [139264, 140032)  uniforms: [layer8][path2][12] f32
#define WS_PARM_OFF 98304
#define WS_UNIF_OFF 139264
#define WS_NEED 140032

__device__ __forceinline__ unsigned short rne_bf16(float f) {
    unsigned u = __builtin_bit_cast(unsigned, f);
    unsigned r = (u + 0x7FFFu + ((u >> 16) & 1u)) >> 16;
    return (unsigned short)r;
}

template <int CTRL>
__device__ __forceinline__ float dpp_add_step(float v) {
    int t = __builtin_amdgcn_update_dpp(0, __builtin_bit_cast(int, v), CTRL, 0xf, 0xf, true);
    return v + __builtin_bit_cast(float, t);
}
// sum across the 16-lane DPP row; result identical in all 16 lanes
__device__ __forceinline__ float reduce16(float v) {
    v = dpp_add_step<0xB1>(v);   // quad_perm(1,0,3,2)
    v = dpp_add_step<0x4E>(v);   // quad_perm(2,3,0,1)
    v = dpp_add_step<0x141>(v);  // row_half_mirror
    v = dpp_add_step<0x140>(v);  // row_mirror
    return v;
}

// ---------------- preprocessing ----------------
__global__ void preproc_kernel(
    const float* __restrict__ embW2, const float* __restrict__ embb2,
    const float* __restrict__ tW, const float* __restrict__ tb,
    const float* __restrict__ t_ln_g, const float* __restrict__ t_ln_b,
    const float* __restrict__ t_gW, const float* __restrict__ t_gb,
    const float* __restrict__ t_bW, const float* __restrict__ t_bb,
    const float* __restrict__ toW, const float* __restrict__ tob,
    const float* __restrict__ sW, const float* __restrict__ sb,
    const float* __restrict__ s_ln_g, const float* __restrict__ s_ln_b,
    const float* __restrict__ s_gW, const float* __restrict__ s_gb,
    const float* __restrict__ s_bW, const float* __restrict__ s_bb,
    const float* __restrict__ soW, const float* __restrict__ sob,
    unsigned short* __restrict__ ws16, float* __restrict__ wsP,
    float* __restrict__ wsU)
{
    const int i = blockIdx.x;
    const int tid = threadIdx.x;
    const int parity = i & 1;
    const int ka = parity ? 2 : 0, pa = parity ? 0 : 2;

    const float* fsrc[6] = {embW2 + i * 1024, embW2 + i * 1024,
                            t_gW + i * 1024, t_bW + i * 1024,
                            s_gW + i * 1024, s_bW + i * 1024};
    for (int e = tid; e < 6144; e += 256) {
        int s = e >> 10, e10 = e & 1023;
        int half = e10 >> 9, ln = (e10 >> 3) & 63, j = e10 & 7;
        int p8 = (ln >> 4) * 8 + j;
        // gamma/beta GEMMs consume the k-interleaved e2 transpose
        int k = (s >= 2) ? ((p8 >> 1) | ((p8 & 1) << 4)) : p8;
        int c = half * 16 + (ln & 15);
        float w = fsrc[s][k * 32 + c];
        unsigned short hv = rne_bf16(w);
        if (s == 1) {
            float whi = __builtin_bit_cast(float, (unsigned)hv << 16);
            hv = rne_bf16(w - whi);
        }
        ws16[i * 6144 + s * 1024 + e10] = hv;
    }

    if (tid < 32) {
        int p = tid >> 4, r = tid & 15;
        const float* W   = (p ? sW : tW) + i * 128;
        const float* b   = (p ? sb : tb) + i * 32;
        const float* lng = (p ? s_ln_g : t_ln_g) + i * 32;
        const float* lnb = (p ? s_ln_b : t_ln_b) + i * 32;
        const float* gb  = (p ? s_gb : t_gb) + i * 32;
        const float* bb  = (p ? s_bb : t_bb) + i * 32;
        const float* ow  = (p ? soW : toW) + i * 128;
        float sc = p ? (2.0f * LOG2E) : 1.0f;   // fold tanh's exp2 arg into s-path
        int cL = r, cH = r + 16;
        float* dst = wsP + i * 640 + p * 320;
        f4 v0 = {W[ka*32+cL]*lng[cL], W[(ka+1)*32+cL]*lng[cL], b[cL]*lng[cL], lng[cL]};
        f4 v1 = {W[ka*32+cH]*lng[cH], W[(ka+1)*32+cH]*lng[cH], b[cH]*lng[cH], lng[cH]};
        f4 v2 = {lnb[cL], lnb[cH], gb[cL], gb[cH]};
        f4 v3 = {bb[cL], bb[cH], ow[cL*4+pa]*sc, ow[cL*4+pa+1]*sc};
        f4 v4 = {ow[cH*4+pa]*sc, ow[cH*4+pa+1]*sc, embb2[i*32+cL], embb2[i*32+cH]};
        *(f4*)(dst + 0*64 + r*4) = v0;
        *(f4*)(dst + 1*64 + r*4) = v1;
        *(f4*)(dst + 2*64 + r*4) = v2;
        *(f4*)(dst + 3*64 + r*4) = v3;
        *(f4*)(dst + 4*64 + r*4) = v4;
    } else if (tid < 34) {
        int p = tid - 32;
        const float* W  = (p ? sW : tW) + i * 128;
        const float* b  = (p ? sb : tb) + i * 32;
        const float* ob = (p ? sob : tob) + i * 4;
        float sc = p ? (2.0f * LOG2E) : 1.0f;
        float S0=0,S1=0,Sb=0,Q00=0,Q11=0,Qbb=0,Q01=0,Q0b=0,Q1b=0;
        for (int c = 0; c < 32; ++c) {
            float w0 = W[ka*32+c], w1 = W[(ka+1)*32+c], bc = b[c];
            S0+=w0; S1+=w1; Sb+=bc;
            Q00+=w0*w0; Q11+=w1*w1; Qbb+=bc*bc;
            Q01+=w0*w1; Q0b+=w0*bc; Q1b+=w1*bc;
        }
        const float inv32 = 1.0f / 32.0f;
        float* u = wsU + (i*2+p)*12;
        u[0]=S0*inv32; u[1]=S1*inv32; u[2]=Sb*inv32;
        u[3]=Q00*inv32; u[4]=2.0f*Q01*inv32; u[5]=2.0f*Q0b*inv32;
        u[6]=Q11*inv32; u[7]=2.0f*Q1b*inv32; u[8]=Qbb*inv32;
        u[9]=ob[pa]*sc*(1.0f/16.0f); u[10]=ob[pa+1]*sc*(1.0f/16.0f);
        u[11]=0.0f;
    }
}

// ---------------- one FiLM path on matrix cores ----------------
__device__ __forceinline__ void film_path(
    const unsigned short* __restrict__ fb, int slotg, int slotb, int lane,
    const bf16x8 a2[2], const f4 pv[5], const float* __restrict__ u,
    const f2 (&zk)[2][4], float (&f0)[2][4], float (&f1)[2][4])
{
    bf16x8 gh0 = *(const bf16x8*)(fb + slotg * 1024 + lane * 8);
    bf16x8 gh1 = *(const bf16x8*)(fb + slotg * 1024 + 512 + lane * 8);
    bf16x8 bh0 = *(const bf16x8*)(fb + slotb * 1024 + lane * 8);
    bf16x8 bh1 = *(const bf16x8*)(fb + slotb * 1024 + 512 + lane * 8);
    float gbL = pv[2][2], gbH = pv[2][3], bbL = pv[3][0], bbH = pv[3][1];
    f4 cg0 = {gbL, gbL, gbL, gbL}, cg1 = {gbH, gbH, gbH, gbH};
    f4 cb0 = {bbL, bbL, bbL, bbL}, cb1 = {bbH, bbH, bbH, bbH};
    f4 gacc[2][2], bacc[2][2];
    #pragma unroll
    for (int t = 0; t < 2; ++t) {
        gacc[t][0] = __builtin_amdgcn_mfma_f32_16x16x32_bf16(a2[t], gh0, cg0, 0, 0, 0);
        gacc[t][1] = __builtin_amdgcn_mfma_f32_16x16x32_bf16(a2[t], gh1, cg1, 0, 0, 0);
        bacc[t][0] = __builtin_amdgcn_mfma_f32_16x16x32_bf16(a2[t], bh0, cb0, 0, 0, 0);
        bacc[t][1] = __builtin_amdgcn_mfma_f32_16x16x32_bf16(a2[t], bh1, cb1, 0, 0, 0);
    }
    float S0=u[0], S1=u[1], Sb=u[2], Q00=u[3], Q01=u[4], Q0b=u[5];
    float Q11=u[6], Q1b=u[7], Qbb=u[8], ob0=u[9], ob1=u[10];
    float wk0L=pv[0][0], wk1L=pv[0][1], bL=pv[0][2], lngL=pv[0][3];
    float wk0H=pv[1][0], wk1H=pv[1][1], bH=pv[1][2], lngH=pv[1][3];
    float lnbL=pv[2][0], lnbH=pv[2][1];
    float owL0=pv[3][2], owL1=pv[3][3], owH0=pv[4][0], owH1=pv[4][1];
    #pragma unroll
    for (int t = 0; t < 2; ++t) {
        #pragma unroll
        for (int q = 0; q < 4; ++q) {
            float za = zk[t][q][0], zb = zk[t][q][1];
            float m = fmaf(za, S0, fmaf(zb, S1, Sb));
            float ex2 = fmaf(za, fmaf(za, Q00, fmaf(zb, Q01, Q0b)),
                             fmaf(zb, fmaf(zb, Q11, Q1b), Qbb));
            float var = fmaxf(fmaf(-m, m, ex2), 0.0f);
            float rstd = __builtin_amdgcn_rsqf(var + LN_EPS);
            float mr = m * rstd;
            float hL = fmaf(za, wk0L, fmaf(zb, wk1L, bL));
            float hH = fmaf(za, wk0H, fmaf(zb, wk1H, bH));
            float nL = fmaf(hL, rstd, fmaf(-mr, lngL, lnbL));
            float nH = fmaf(hH, rstd, fmaf(-mr, lngH, lnbH));
            float gL = gacc[t][0][q], gH = gacc[t][1][q];
            float btL = bacc[t][0][q], btH = bacc[t][1][q];
            float thL = fmaxf(fmaf(gL, nL, nL + btL), 0.0f);
            float thH = fmaxf(fmaf(gH, nH, nH + btH), 0.0f);
            float p0 = fmaf(thL, owL0, fmaf(thH, owH0, ob0));
            float p1 = fmaf(thL, owL1, fmaf(thH, owH1, ob1));
            f0[t][q] = reduce16(p0);
            f1[t][q] = reduce16(p1);
        }
    }
}

__device__ __forceinline__ void layer_body(
    int i, const unsigned short* __restrict__ ws16,
    const float* __restrict__ wsP, const float* __restrict__ wsU,
    const float* __restrict__ embW1, const float* __restrict__ embb1,
    int lane, int r, int g, unsigned char* T, const f4 y4[2],
    f2 (&zk)[2][4], f2 (&zt)[2][4], f4& ld0, f4& ld1)
{
    const unsigned short* fb = ws16 + i * 6144;
    const float* pP = wsP + i * 640;
    const float* uT = wsU + i * 24;
    const float* uS = uT + 12;

    f4 ptv[5];
    #pragma unroll
    for (int v = 0; v < 5; ++v) ptv[v] = *(const f4*)(pP + v * 64 + r * 4);

    // ---- e1 = relu(y @ W1 + b1) directly in A-fragment layout ----
    const float* W1 = embW1 + i * 128;
    f4 w1a[4], w1b[4];
    #pragma unroll
    for (int c = 0; c < 4; ++c) {
        w1a[c] = *(const f4*)(W1 + c * 32 + g * 8);
        w1b[c] = *(const f4*)(W1 + c * 32 + g * 8 + 4);
    }
    f4 b1a = *(const f4*)(embb1 + i * 32 + g * 8);
    f4 b1b = *(const f4*)(embb1 + i * 32 + g * 8 + 4);
    bf16x8 a1[2];
    #pragma unroll
    for (int t = 0; t < 2; ++t) {
        #pragma unroll
        for (int j = 0; j < 8; ++j) {
            float acc = (j < 4) ? b1a[j & 3] : b1b[j & 3];
            #pragma unroll
            for (int c = 0; c < 4; ++c)
                acc = fmaf(y4[t][c], (j < 4) ? w1a[c][j & 3] : w1b[c][j & 3], acc);
            a1[t][j] = (short)rne_bf16(fmaxf(acc, 0.0f));
        }
    }

    // ---- e2 = relu(e1 @ W2 + b2), bias in accumulator init, hi+lo weights ----
    bf16x8 w2h0 = *(const bf16x8*)(fb + lane * 8);
    bf16x8 w2h1 = *(const bf16x8*)(fb + 512 + lane * 8);
    bf16x8 w2l0 = *(const bf16x8*)(fb + 1024 + lane * 8);
    bf16x8 w2l1 = *(const bf16x8*)(fb + 1536 + lane * 8);
    float b2L = ptv[4][2], b2H = ptv[4][3];
    f4 c2L = {b2L, b2L, b2L, b2L}, c2H = {b2H, b2H, b2H, b2H};
    f4 e2a[2][2];
    #pragma unroll
    for (int t = 0; t < 2; ++t) {
        e2a[t][0] = __builtin_amdgcn_mfma_f32_16x16x32_bf16(a1[t], w2h0, c2L, 0, 0, 0);
        e2a[t][0] = __builtin_amdgcn_mfma_f32_16x16x32_bf16(a1[t], w2l0, e2a[t][0], 0, 0, 0);
        e2a[t][1] = __builtin_amdgcn_mfma_f32_16x16x32_bf16(a1[t], w2h1, c2H, 0, 0, 0);
        e2a[t][1] = __builtin_amdgcn_mfma_f32_16x16x32_bf16(a1[t], w2l1, e2a[t][1], 0, 0, 0);
    }

    // ---- D-layout -> A-layout transpose through LDS (k-interleaved pack) ----
    #pragma unroll
    for (int t = 0; t < 2; ++t)
        #pragma unroll
        for (int q = 0; q < 4; ++q) {
            float vl = fmaxf(e2a[t][0][q], 0.0f);
            float vh = fmaxf(e2a[t][1][q], 0.0f);
            unsigned w = (unsigned)rne_bf16(vl) | ((unsigned)rne_bf16(vh) << 16);
            *(unsigned*)(T + (16 * t + 4 * g + q) * 80 + r * 4) = w;
        }
    asm volatile("s_waitcnt lgkmcnt(0)" ::: "memory");
    __builtin_amdgcn_sched_barrier(0);
    bf16x8 a2[2];
    #pragma unroll
    for (int t = 0; t < 2; ++t)
        a2[t] = *(const bf16x8*)(T + (16 * t + r) * 80 + g * 16);

    // ---- t and s FiLM paths ----
    float tf0[2][4], tf1[2][4], sf0[2][4], sf1[2][4];
    film_path(fb, 2, 3, lane, a2, ptv, uT, zk, tf0, tf1);
    f4 psv[5];
    #pragma unroll
    for (int v = 0; v < 5; ++v) psv[v] = *(const f4*)(pP + 320 + v * 64 + r * 4);
    film_path(fb, 4, 5, lane, a2, psv, uS, zk, sf0, sf1);

    // ---- coupling update: sf already scaled by 2*log2e; tanh = 1 - 2/(exp2(x)+1) ----
    #pragma unroll
    for (int t = 0; t < 2; ++t)
        #pragma unroll
        for (int q = 0; q < 4; ++q) {
            float x0 = fminf(fmaxf(sf0[t][q], -60.0f), 60.0f);
            float x1 = fminf(fmaxf(sf1[t][q], -60.0f), 60.0f);
            float e0 = __builtin_amdgcn_exp2f(x0);
            float e1_ = __builtin_amdgcn_exp2f(x1);
            float r0 = __builtin_amdgcn_rcpf(e0 + 1.0f);
            float r1 = __builtin_amdgcn_rcpf(e1_ + 1.0f);
            float s0 = fmaf(-2.0f, r0, 1.0f);
            float s1 = fmaf(-2.0f, r1, 1.0f);
            float eA = __builtin_amdgcn_exp2f(s0 * LOG2E);
            float eB = __builtin_amdgcn_exp2f(s1 * LOG2E);
            zt[t][q][0] = fmaf(zt[t][q][0], eA, tf0[t][q]);
            zt[t][q][1] = fmaf(zt[t][q][1], eB, tf1[t][q]);
            if (t == 0) ld0[q] += s0 + s1; else ld1[q] += s0 + s1;
        }
}

__global__ __launch_bounds__(256, 1) void realnvp_mfma(
    const float* __restrict__ x, const float* __restrict__ y,
    const float* __restrict__ embW1, const float* __restrict__ embb1,
    const unsigned short* __restrict__ ws16,
    const float* __restrict__ wsP, const float* __restrict__ wsU,
    float* __restrict__ out_z, float* __restrict__ out_ld)
{
    __shared__ __align__(16) unsigned char ldsbuf[4 * 2560];
    const int lane = threadIdx.x & 63;
    const int wv = threadIdx.x >> 6;
    const int r = lane & 15, g = lane >> 4;
    unsigned char* T = ldsbuf + wv * 2560;   // 32 rows x 80B pitch
    const int row0 = (blockIdx.x * 4 + wv) * 32;

    // zA = dims(0,1), zB = dims(2,3); rows replicated across the 16-lane group
    f2 zA[2][4], zB[2][4];
    #pragma unroll
    for (int t = 0; t < 2; ++t)
        #pragma unroll
        for (int q = 0; q < 4; ++q) {
            f4 xv = *(const f4*)(x + (size_t)(row0 + 16 * t + 4 * g + q) * 4);
            zA[t][q][0] = xv.x; zA[t][q][1] = xv.y;
            zB[t][q][0] = xv.z; zB[t][q][1] = xv.w;
        }
    f4 y4[2];
    #pragma unroll
    for (int t = 0; t < 2; ++t)
        y4[t] = *(const f4*)(y + (size_t)(row0 + 16 * t + r) * 4);
    f4 ld0 = {0.f, 0.f, 0.f, 0.f}, ld1 = {0.f, 0.f, 0.f, 0.f};

    #pragma unroll 1
    for (int ii = 0; ii < 4; ++ii) {
        layer_body(2 * ii,     ws16, wsP, wsU, embW1, embb1, lane, r, g, T, y4, zA, zB, ld0, ld1);
        layer_body(2 * ii + 1, ws16, wsP, wsU, embW1, embb1, lane, r, g, T, y4, zB, zA, ld0, ld1);
    }

    if (r == 0) {
        #pragma unroll
        for (int t = 0; t < 2; ++t)
            #pragma unroll
            for (int q = 0; q < 4; ++q) {
                f4 zo = {zA[t][q][0], zA[t][q][1], zB[t][q][0], zB[t][q][1]};
                *(f4*)(out_z + (size_t)(row0 + 16 * t + 4 * g + q) * 4) = zo;
            }
        *(f4*)(out_ld + row0 + 4 * g) = ld0;
        *(f4*)(out_ld + row0 + 16 + 4 * g) = ld1;
    }
}

extern "C" void kernel_launch(void* const* d_in, const int* in_sizes, int n_in,
                              void* d_out, int out_size, void* d_ws, size_t ws_size,
                              hipStream_t stream) {
    const float* x      = (const float*)d_in[0];
    const float* y      = (const float*)d_in[1];
    const float* embW1  = (const float*)d_in[2];
    const float* embb1  = (const float*)d_in[3];
    const float* embW2  = (const float*)d_in[4];
    const float* embb2  = (const float*)d_in[5];
    const float* tW     = (const float*)d_in[6];
    const float* tb     = (const float*)d_in[7];
    const float* t_ln_g = (const float*)d_in[8];
    const float* t_ln_b = (const float*)d_in[9];
    const float* t_gW   = (const float*)d_in[10];
    const float* t_gb   = (const float*)d_in[11];
    const float* t_bW   = (const float*)d_in[12];
    const float* t_bb   = (const float*)d_in[13];
    const float* toW    = (const float*)d_in[14];
    const float* tob    = (const float*)d_in[15];
    const float* sW     = (const float*)d_in[16];
    const float* sb     = (const float*)d_in[17];
    const float* s_ln_g = (const float*)d_in[18];
    const float* s_ln_b = (const float*)d_in[19];
    const float* s_gW   = (const float*)d_in[20];
    const float* s_gb   = (const float*)d_in[21];
    const float* s_bW   = (const float*)d_in[22];
    const float* s_bb   = (const float*)d_in[23];
    const float* soW    = (const float*)d_in[24];
    const float* sob    = (const float*)d_in[25];

    if (ws_size < WS_NEED) return;
    unsigned short* ws16 = (unsigned short*)d_ws;
    float* wsP = (float*)((char*)d_ws + WS_PARM_OFF);
    float* wsU = (float*)((char*)d_ws + WS_UNIF_OFF);

    int B = in_sizes[0] / 4;
    float* out_z  = (float*)d_out;
    float* out_ld = out_z + (size_t)B * 4;

    hipLaunchKernelGGL(preproc_kernel, dim3(8), dim3(256), 0, stream,
                       embW2, embb2, tW, tb, t_ln_g, t_ln_b, t_gW, t_gb,
                       t_bW, t_bb, toW, tob, sW, sb, s_ln_g, s_ln_b,
                       s_gW, s_gb, s_bW, s_bb, soW, sob, ws16, wsP, wsU);
    hipLaunchKernelGGL(realnvp_mfma, dim3(B / 128), dim3(256), 0, stream,
                       x, y, embW1, embb1, ws16, wsP, wsU, out_z, out_ld);
}

// Round 8
// 142.879 us; speedup vs baseline: 17.7660x; 1.0161x over previous
//
#include <hip/hip_runtime.h>
#include <math.h>

#define LN_EPS 1e-5f
#define LOG2E 1.44269504088896f

typedef float f4 __attribute__((ext_vector_type(4)));
typedef float f2 __attribute__((ext_vector_type(2)));
typedef int   i4 __attribute__((ext_vector_type(4)));
typedef short bf16x8 __attribute__((ext_vector_type(8)));

// d_ws layout (bytes):
//   [0, 98304)        frags: [layer8][slot6][half2][lane64][j8] bf16
//                     slots: 0=W2hi 1=W2lo 2=tG 3=tB 4=sG 5=sB
//   [98304, 139264)   params: [layer8][path2][vec5][r16][4] f32
//   [139264, 140032)  uniforms: [layer8][path2][12] f32
#define WS_PARM_OFF 98304
#define WS_UNIF_OFF 139264
#define WS_NEED 140032

__device__ __forceinline__ unsigned short rne_bf16(float f) {
    unsigned u = __builtin_bit_cast(unsigned, f);
    unsigned r = (u + 0x7FFFu + ((u >> 16) & 1u)) >> 16;
    return (unsigned short)r;
}

template <int CTRL>
__device__ __forceinline__ float dpp_add_step(float v) {
    int t = __builtin_amdgcn_update_dpp(0, __builtin_bit_cast(int, v), CTRL, 0xf, 0xf, true);
    return v + __builtin_bit_cast(float, t);
}
// sum across the 16-lane DPP row; result identical in all 16 lanes
__device__ __forceinline__ float reduce16(float v) {
    v = dpp_add_step<0xB1>(v);   // quad_perm(1,0,3,2)
    v = dpp_add_step<0x4E>(v);   // quad_perm(2,3,0,1)
    v = dpp_add_step<0x141>(v);  // row_half_mirror
    v = dpp_add_step<0x140>(v);  // row_mirror
    return v;
}

// ---------------- preprocessing ----------------
__global__ void preproc_kernel(
    const float* __restrict__ embW2, const float* __restrict__ embb2,
    const float* __restrict__ tW, const float* __restrict__ tb,
    const float* __restrict__ t_ln_g, const float* __restrict__ t_ln_b,
    const float* __restrict__ t_gW, const float* __restrict__ t_gb,
    const float* __restrict__ t_bW, const float* __restrict__ t_bb,
    const float* __restrict__ toW, const float* __restrict__ tob,
    const float* __restrict__ sW, const float* __restrict__ sb,
    const float* __restrict__ s_ln_g, const float* __restrict__ s_ln_b,
    const float* __restrict__ s_gW, const float* __restrict__ s_gb,
    const float* __restrict__ s_bW, const float* __restrict__ s_bb,
    const float* __restrict__ soW, const float* __restrict__ sob,
    unsigned short* __restrict__ ws16, float* __restrict__ wsP,
    float* __restrict__ wsU)
{
    const int i = blockIdx.x;
    const int tid = threadIdx.x;
    const int parity = i & 1;
    const int ka = parity ? 2 : 0, pa = parity ? 0 : 2;

    const float* fsrc[6] = {embW2 + i * 1024, embW2 + i * 1024,
                            t_gW + i * 1024, t_bW + i * 1024,
                            s_gW + i * 1024, s_bW + i * 1024};
    for (int e = tid; e < 6144; e += 256) {
        int s = e >> 10, e10 = e & 1023;
        int half = e10 >> 9, ln = (e10 >> 3) & 63, j = e10 & 7;
        int p8 = (ln >> 4) * 8 + j;
        // gamma/beta GEMMs consume the k-interleaved e2 transpose
        int k = (s >= 2) ? ((p8 >> 1) | ((p8 & 1) << 4)) : p8;
        int c = half * 16 + (ln & 15);
        float w = fsrc[s][k * 32 + c];
        unsigned short hv = rne_bf16(w);
        if (s == 1) {
            float whi = __builtin_bit_cast(float, (unsigned)hv << 16);
            hv = rne_bf16(w - whi);
        }
        ws16[i * 6144 + s * 1024 + e10] = hv;
    }

    if (tid < 32) {
        int p = tid >> 4, r = tid & 15;
        const float* W   = (p ? sW : tW) + i * 128;
        const float* b   = (p ? sb : tb) + i * 32;
        const float* lng = (p ? s_ln_g : t_ln_g) + i * 32;
        const float* lnb = (p ? s_ln_b : t_ln_b) + i * 32;
        const float* gb  = (p ? s_gb : t_gb) + i * 32;
        const float* bb  = (p ? s_bb : t_bb) + i * 32;
        const float* ow  = (p ? soW : toW) + i * 128;
        float sc = p ? (2.0f * LOG2E) : 1.0f;   // fold tanh's exp2 arg into s-path
        int cL = r, cH = r + 16;
        float* dst = wsP + i * 640 + p * 320;
        f4 v0 = {W[ka*32+cL]*lng[cL], W[(ka+1)*32+cL]*lng[cL], b[cL]*lng[cL], lng[cL]};
        f4 v1 = {W[ka*32+cH]*lng[cH], W[(ka+1)*32+cH]*lng[cH], b[cH]*lng[cH], lng[cH]};
        f4 v2 = {lnb[cL], lnb[cH], gb[cL], gb[cH]};
        f4 v3 = {bb[cL], bb[cH], ow[cL*4+pa]*sc, ow[cL*4+pa+1]*sc};
        f4 v4 = {ow[cH*4+pa]*sc, ow[cH*4+pa+1]*sc, embb2[i*32+cL], embb2[i*32+cH]};
        *(f4*)(dst + 0*64 + r*4) = v0;
        *(f4*)(dst + 1*64 + r*4) = v1;
        *(f4*)(dst + 2*64 + r*4) = v2;
        *(f4*)(dst + 3*64 + r*4) = v3;
        *(f4*)(dst + 4*64 + r*4) = v4;
    } else if (tid < 34) {
        int p = tid - 32;
        const float* W  = (p ? sW : tW) + i * 128;
        const float* b  = (p ? sb : tb) + i * 32;
        const float* ob = (p ? sob : tob) + i * 4;
        float sc = p ? (2.0f * LOG2E) : 1.0f;
        float S0=0,S1=0,Sb=0,Q00=0,Q11=0,Qbb=0,Q01=0,Q0b=0,Q1b=0;
        for (int c = 0; c < 32; ++c) {
            float w0 = W[ka*32+c], w1 = W[(ka+1)*32+c], bc = b[c];
            S0+=w0; S1+=w1; Sb+=bc;
            Q00+=w0*w0; Q11+=w1*w1; Qbb+=bc*bc;
            Q01+=w0*w1; Q0b+=w0*bc; Q1b+=w1*bc;
        }
        const float inv32 = 1.0f / 32.0f;
        float* u = wsU + (i*2+p)*12;
        u[0]=S0*inv32; u[1]=S1*inv32; u[2]=Sb*inv32;
        u[3]=Q00*inv32; u[4]=2.0f*Q01*inv32; u[5]=2.0f*Q0b*inv32;
        u[6]=Q11*inv32; u[7]=2.0f*Q1b*inv32; u[8]=Qbb*inv32;
        u[9]=ob[pa]*sc*(1.0f/16.0f); u[10]=ob[pa+1]*sc*(1.0f/16.0f);
        u[11]=0.0f;
    }
}

// ---------------- one FiLM path on matrix cores ----------------
__device__ __forceinline__ void film_path(
    const unsigned short* __restrict__ fb, int slotg, int slotb, int lane,
    const bf16x8 a2[2], const f4 pv[5], const float* __restrict__ u,
    const f2 (&zk)[2][4], float (&f0)[2][4], float (&f1)[2][4])
{
    bf16x8 gh0 = *(const bf16x8*)(fb + slotg * 1024 + lane * 8);
    bf16x8 gh1 = *(const bf16x8*)(fb + slotg * 1024 + 512 + lane * 8);
    bf16x8 bh0 = *(const bf16x8*)(fb + slotb * 1024 + lane * 8);
    bf16x8 bh1 = *(const bf16x8*)(fb + slotb * 1024 + 512 + lane * 8);
    float gbL = pv[2][2], gbH = pv[2][3], bbL = pv[3][0], bbH = pv[3][1];
    f4 cg0 = {gbL, gbL, gbL, gbL}, cg1 = {gbH, gbH, gbH, gbH};
    f4 cb0 = {bbL, bbL, bbL, bbL}, cb1 = {bbH, bbH, bbH, bbH};
    f4 gacc[2][2], bacc[2][2];
    #pragma unroll
    for (int t = 0; t < 2; ++t) {
        gacc[t][0] = __builtin_amdgcn_mfma_f32_16x16x32_bf16(a2[t], gh0, cg0, 0, 0, 0);
        gacc[t][1] = __builtin_amdgcn_mfma_f32_16x16x32_bf16(a2[t], gh1, cg1, 0, 0, 0);
        bacc[t][0] = __builtin_amdgcn_mfma_f32_16x16x32_bf16(a2[t], bh0, cb0, 0, 0, 0);
        bacc[t][1] = __builtin_amdgcn_mfma_f32_16x16x32_bf16(a2[t], bh1, cb1, 0, 0, 0);
    }
    float S0=u[0], S1=u[1], Sb=u[2], Q00=u[3], Q01=u[4], Q0b=u[5];
    float Q11=u[6], Q1b=u[7], Qbb=u[8], ob0=u[9], ob1=u[10];
    float wk0L=pv[0][0], wk1L=pv[0][1], bL=pv[0][2], lngL=pv[0][3];
    float wk0H=pv[1][0], wk1H=pv[1][1], bH=pv[1][2], lngH=pv[1][3];
    float lnbL=pv[2][0], lnbH=pv[2][1];
    float owL0=pv[3][2], owL1=pv[3][3], owH0=pv[4][0], owH1=pv[4][1];
    #pragma unroll
    for (int t = 0; t < 2; ++t) {
        #pragma unroll
        for (int q = 0; q < 4; ++q) {
            float za = zk[t][q][0], zb = zk[t][q][1];
            float m = fmaf(za, S0, fmaf(zb, S1, Sb));
            float ex2 = fmaf(za, fmaf(za, Q00, fmaf(zb, Q01, Q0b)),
                             fmaf(zb, fmaf(zb, Q11, Q1b), Qbb));
            float var = fmaxf(fmaf(-m, m, ex2), 0.0f);
            float rstd = __builtin_amdgcn_rsqf(var + LN_EPS);
            float mr = m * rstd;
            float hL = fmaf(za, wk0L, fmaf(zb, wk1L, bL));
            float hH = fmaf(za, wk0H, fmaf(zb, wk1H, bH));
            float nL = fmaf(hL, rstd, fmaf(-mr, lngL, lnbL));
            float nH = fmaf(hH, rstd, fmaf(-mr, lngH, lnbH));
            float gL = gacc[t][0][q], gH = gacc[t][1][q];
            float btL = bacc[t][0][q], btH = bacc[t][1][q];
            float thL = fmaxf(fmaf(gL, nL, nL + btL), 0.0f);
            float thH = fmaxf(fmaf(gH, nH, nH + btH), 0.0f);
            float p0 = fmaf(thL, owL0, fmaf(thH, owH0, ob0));
            float p1 = fmaf(thL, owL1, fmaf(thH, owH1, ob1));
            f0[t][q] = reduce16(p0);
            f1[t][q] = reduce16(p1);
        }
    }
}

__device__ __forceinline__ void layer_body(
    int i, const unsigned short* __restrict__ ws16,
    const float* __restrict__ wsP, const float* __restrict__ wsU,
    const float* __restrict__ embW1, const float* __restrict__ embb1,
    int lane, int r, int g, unsigned char* T, const f4 y4[2],
    f2 (&zk)[2][4], f2 (&zt)[2][4], f4& ld0, f4& ld1)
{
    const unsigned short* fb = ws16 + i * 6144;
    const float* pP = wsP + i * 640;
    const float* uT = wsU + (i * 2) * 12;
    const float* uS = uT + 12;

    f4 ptv[5];
    #pragma unroll
    for (int v = 0; v < 5; ++v) ptv[v] = *(const f4*)(pP + v * 64 + r * 4);

    // ---- e1 = relu(y @ W1 + b1) directly in A-fragment layout ----
    const float* W1 = embW1 + i * 128;
    f4 w1a[4], w1b[4];
    #pragma unroll
    for (int c = 0; c < 4; ++c) {
        w1a[c] = *(const f4*)(W1 + c * 32 + g * 8);
        w1b[c] = *(const f4*)(W1 + c * 32 + g * 8 + 4);
    }
    f4 b1a = *(const f4*)(embb1 + i * 32 + g * 8);
    f4 b1b = *(const f4*)(embb1 + i * 32 + g * 8 + 4);
    bf16x8 a1[2];
    #pragma unroll
    for (int t = 0; t < 2; ++t) {
        #pragma unroll
        for (int j = 0; j < 8; ++j) {
            float acc = (j < 4) ? b1a[j & 3] : b1b[j & 3];
            #pragma unroll
            for (int c = 0; c < 4; ++c)
                acc = fmaf(y4[t][c], (j < 4) ? w1a[c][j & 3] : w1b[c][j & 3], acc);
            a1[t][j] = (short)rne_bf16(fmaxf(acc, 0.0f));
        }
    }

    // ---- e2 = relu(e1 @ W2 + b2) via MFMA (hi+lo weights, bias in C) ----
    bf16x8 w2h0 = *(const bf16x8*)(fb + lane * 8);
    bf16x8 w2h1 = *(const bf16x8*)(fb + 512 + lane * 8);
    bf16x8 w2l0 = *(const bf16x8*)(fb + 1024 + lane * 8);
    bf16x8 w2l1 = *(const bf16x8*)(fb + 1536 + lane * 8);
    float b2L = ptv[4][2], b2H = ptv[4][3];
    f4 c2L = {b2L, b2L, b2L, b2L}, c2H = {b2H, b2H, b2H, b2H};
    f4 e2a[2][2];
    #pragma unroll
    for (int t = 0; t < 2; ++t) {
        e2a[t][0] = __builtin_amdgcn_mfma_f32_16x16x32_bf16(a1[t], w2h0, c2L, 0, 0, 0);
        e2a[t][0] = __builtin_amdgcn_mfma_f32_16x16x32_bf16(a1[t], w2l0, e2a[t][0], 0, 0, 0);
        e2a[t][1] = __builtin_amdgcn_mfma_f32_16x16x32_bf16(a1[t], w2h1, c2H, 0, 0, 0);
        e2a[t][1] = __builtin_amdgcn_mfma_f32_16x16x32_bf16(a1[t], w2l1, e2a[t][1], 0, 0, 0);
    }

    // ---- D-layout -> A-layout transpose through LDS (k-interleaved pack) ----
    #pragma unroll
    for (int t = 0; t < 2; ++t)
        #pragma unroll
        for (int q = 0; q < 4; ++q) {
            int rowl = 16 * t + 4 * g + q;
            float vl = fmaxf(e2a[t][0][q], 0.0f);
            float vh = fmaxf(e2a[t][1][q], 0.0f);
            unsigned w = (unsigned)rne_bf16(vl) | ((unsigned)rne_bf16(vh) << 16);
            *(unsigned*)(T + rowl * 80 + r * 4) = w;
        }
    asm volatile("s_waitcnt lgkmcnt(0)" ::: "memory");
    __builtin_amdgcn_sched_barrier(0);
    bf16x8 a2[2];
    a2[0] = *(const bf16x8*)(T + r * 80 + g * 16);
    a2[1] = *(const bf16x8*)(T + (16 + r) * 80 + g * 16);

    // ---- t and s FiLM paths ----
    float tf0[2][4], tf1[2][4], sf0[2][4], sf1[2][4];
    film_path(fb, 2, 3, lane, a2, ptv, uT, zk, tf0, tf1);
    f4 psv[5];
    #pragma unroll
    for (int v = 0; v < 5; ++v) psv[v] = *(const f4*)(pP + 320 + v * 64 + r * 4);
    film_path(fb, 4, 5, lane, a2, psv, uS, zk, sf0, sf1);

    // ---- coupling update: sf already scaled by 2*log2e; tanh = 1 - 2/(exp2(x)+1) ----
    // No clamp needed: exp2(+inf)->inf -> rcp->0 -> s=1; exp2(-inf)->0 -> rcp(1)=1 -> s=-1.
    #pragma unroll
    for (int t = 0; t < 2; ++t)
        #pragma unroll
        for (int q = 0; q < 4; ++q) {
            float x0 = sf0[t][q];
            float x1 = sf1[t][q];
            float e0 = __builtin_amdgcn_exp2f(x0);
            float e1_ = __builtin_amdgcn_exp2f(x1);
            float r0 = __builtin_amdgcn_rcpf(e0 + 1.0f);
            float r1 = __builtin_amdgcn_rcpf(e1_ + 1.0f);
            float s0 = fmaf(-2.0f, r0, 1.0f);
            float s1 = fmaf(-2.0f, r1, 1.0f);
            float eA = __builtin_amdgcn_exp2f(s0 * LOG2E);
            float eB = __builtin_amdgcn_exp2f(s1 * LOG2E);
            zt[t][q][0] = fmaf(zt[t][q][0], eA, tf0[t][q]);
            zt[t][q][1] = fmaf(zt[t][q][1], eB, tf1[t][q]);
            if (t == 0) ld0[q] += s0 + s1; else ld1[q] += s0 + s1;
        }
}

__global__ __launch_bounds__(256, 1) void realnvp_mfma(
    const float* __restrict__ x, const float* __restrict__ y,
    const float* __restrict__ embW1, const float* __restrict__ embb1,
    const unsigned short* __restrict__ ws16,
    const float* __restrict__ wsP, const float* __restrict__ wsU,
    float* __restrict__ out_z, float* __restrict__ out_ld)
{
    __shared__ __align__(16) unsigned char ldsbuf[4 * 2560];
    const int lane = threadIdx.x & 63;
    const int wv = threadIdx.x >> 6;
    const int r = lane & 15, g = lane >> 4;
    unsigned char* T = ldsbuf + wv * 2560;   // 32 rows x 80B pitch
    const int row0 = (blockIdx.x * 4 + wv) * 32;

    // zA = dims(0,1), zB = dims(2,3); rows replicated across the 16-lane group
    f2 zA[2][4], zB[2][4];
    #pragma unroll
    for (int t = 0; t < 2; ++t)
        #pragma unroll
        for (int q = 0; q < 4; ++q) {
            f4 xv = *(const f4*)(x + (size_t)(row0 + 16 * t + 4 * g + q) * 4);
            zA[t][q][0] = xv.x; zA[t][q][1] = xv.y;
            zB[t][q][0] = xv.z; zB[t][q][1] = xv.w;
        }
    f4 y4[2];
    #pragma unroll
    for (int t = 0; t < 2; ++t)
        y4[t] = *(const f4*)(y + (size_t)(row0 + 16 * t + r) * 4);
    f4 ld0 = {0.f, 0.f, 0.f, 0.f}, ld1 = {0.f, 0.f, 0.f, 0.f};

    #pragma unroll 1
    for (int ii = 0; ii < 4; ++ii) {
        layer_body(2 * ii,     ws16, wsP, wsU, embW1, embb1, lane, r, g, T, y4, zA, zB, ld0, ld1);
        layer_body(2 * ii + 1, ws16, wsP, wsU, embW1, embb1, lane, r, g, T, y4, zB, zA, ld0, ld1);
    }

    if (r == 0) {
        #pragma unroll
        for (int t = 0; t < 2; ++t)
            #pragma unroll
            for (int q = 0; q < 4; ++q) {
                f4 zo = {zA[t][q][0], zA[t][q][1], zB[t][q][0], zB[t][q][1]};
                *(f4*)(out_z + (size_t)(row0 + 16 * t + 4 * g + q) * 4) = zo;
            }
        *(f4*)(out_ld + row0 + 4 * g) = ld0;
        *(f4*)(out_ld + row0 + 16 + 4 * g) = ld1;
    }
}

extern "C" void kernel_launch(void* const* d_in, const int* in_sizes, int n_in,
                              void* d_out, int out_size, void* d_ws, size_t ws_size,
                              hipStream_t stream) {
    const float* x      = (const float*)d_in[0];
    const float* y      = (const float*)d_in[1];
    const float* embW1  = (const float*)d_in[2];
    const float* embb1  = (const float*)d_in[3];
    const float* embW2  = (const float*)d_in[4];
    const float* embb2  = (const float*)d_in[5];
    const float* tW     = (const float*)d_in[6];
    const float* tb     = (const float*)d_in[7];
    const float* t_ln_g = (const float*)d_in[8];
    const float* t_ln_b = (const float*)d_in[9];
    const float* t_gW   = (const float*)d_in[10];
    const float* t_gb   = (const float*)d_in[11];
    const float* t_bW   = (const float*)d_in[12];
    const float* t_bb   = (const float*)d_in[13];
    const float* toW    = (const float*)d_in[14];
    const float* tob    = (const float*)d_in[15];
    const float* sW     = (const float*)d_in[16];
    const float* sb     = (const float*)d_in[17];
    const float* s_ln_g = (const float*)d_in[18];
    const float* s_ln_b = (const float*)d_in[19];
    const float* s_gW   = (const float*)d_in[20];
    const float* s_gb   = (const float*)d_in[21];
    const float* s_bW   = (const float*)d_in[22];
    const float* s_bb   = (const float*)d_in[23];
    const float* soW    = (const float*)d_in[24];
    const float* sob    = (const float*)d_in[25];

    if (ws_size < WS_NEED) return;
    unsigned short* ws16 = (unsigned short*)d_ws;
    float* wsP = (float*)((char*)d_ws + WS_PARM_OFF);
    float* wsU = (float*)((char*)d_ws + WS_UNIF_OFF);

    int B = in_sizes[0] / 4;
    float* out_z  = (float*)d_out;
    float* out_ld = out_z + (size_t)B * 4;

    hipLaunchKernelGGL(preproc_kernel, dim3(8), dim3(256), 0, stream,
                       embW2, embb2, tW, tb, t_ln_g, t_ln_b, t_gW, t_gb,
                       t_bW, t_bb, toW, tob, sW, sb, s_ln_g, s_ln_b,
                       s_gW, s_gb, s_bW, s_bb, soW, sob, ws16, wsP, wsU);
    hipLaunchKernelGGL(realnvp_mfma, dim3(B / 128), dim3(256), 0, stream,
                       x, y, embW1, embb1, ws16, wsP, wsU, out_z, out_ld);
}

// Round 9
// 139.245 us; speedup vs baseline: 18.2297x; 1.0261x over previous
//
#include <hip/hip_runtime.h>
#include <math.h>

#define LN_EPS 1e-5f
#define LOG2E 1.44269504088896f

typedef float f4 __attribute__((ext_vector_type(4)));
typedef float f2 __attribute__((ext_vector_type(2)));
typedef int   i4 __attribute__((ext_vector_type(4)));
typedef short bf16x8 __attribute__((ext_vector_type(8)));

// d_ws layout (bytes):
//   [0, 98304)        frags: [layer8][slot6][half2][lane64][j8] bf16
//                     slots: 0=W2hi 1=W2lo 2=tG 3=tB 4=sG 5=sB
//   [98304, 139264)   params: [layer8][path2][vec5][r16][4] f32
//   [139264, 140032)  uniforms: [layer8][path2][12] f32
#define WS_PARM_OFF 98304
#define WS_UNIF_OFF 139264
#define WS_NEED 140032

__device__ __forceinline__ unsigned short rne_bf16(float f) {
    unsigned u = __builtin_bit_cast(unsigned, f);
    unsigned r = (u + 0x7FFFu + ((u >> 16) & 1u)) >> 16;
    return (unsigned short)r;
}

// packed f32->bf16 convert (RNE), one VALU op for two conversions [T12 primitive]
__device__ __forceinline__ unsigned cvt_pk_bf16(float lo, float hi) {
    unsigned r;
    asm("v_cvt_pk_bf16_f32 %0, %1, %2" : "=v"(r) : "v"(lo), "v"(hi));
    return r;
}

template <int CTRL>
__device__ __forceinline__ float dpp_add_step(float v) {
    int t = __builtin_amdgcn_update_dpp(0, __builtin_bit_cast(int, v), CTRL, 0xf, 0xf, true);
    return v + __builtin_bit_cast(float, t);
}
// sum across the 16-lane DPP row; result identical in all 16 lanes
__device__ __forceinline__ float reduce16(float v) {
    v = dpp_add_step<0xB1>(v);   // quad_perm(1,0,3,2)
    v = dpp_add_step<0x4E>(v);   // quad_perm(2,3,0,1)
    v = dpp_add_step<0x141>(v);  // row_half_mirror
    v = dpp_add_step<0x140>(v);  // row_mirror
    return v;
}

// ---------------- preprocessing ----------------
__global__ void preproc_kernel(
    const float* __restrict__ embW2, const float* __restrict__ embb2,
    const float* __restrict__ tW, const float* __restrict__ tb,
    const float* __restrict__ t_ln_g, const float* __restrict__ t_ln_b,
    const float* __restrict__ t_gW, const float* __restrict__ t_gb,
    const float* __restrict__ t_bW, const float* __restrict__ t_bb,
    const float* __restrict__ toW, const float* __restrict__ tob,
    const float* __restrict__ sW, const float* __restrict__ sb,
    const float* __restrict__ s_ln_g, const float* __restrict__ s_ln_b,
    const float* __restrict__ s_gW, const float* __restrict__ s_gb,
    const float* __restrict__ s_bW, const float* __restrict__ s_bb,
    const float* __restrict__ soW, const float* __restrict__ sob,
    unsigned short* __restrict__ ws16, float* __restrict__ wsP,
    float* __restrict__ wsU)
{
    const int i = blockIdx.x;
    const int tid = threadIdx.x;
    const int parity = i & 1;
    const int ka = parity ? 2 : 0, pa = parity ? 0 : 2;

    const float* fsrc[6] = {embW2 + i * 1024, embW2 + i * 1024,
                            t_gW + i * 1024, t_bW + i * 1024,
                            s_gW + i * 1024, s_bW + i * 1024};
    for (int e = tid; e < 6144; e += 256) {
        int s = e >> 10, e10 = e & 1023;
        int half = e10 >> 9, ln = (e10 >> 3) & 63, j = e10 & 7;
        int p8 = (ln >> 4) * 8 + j;
        // gamma/beta GEMMs consume the k-interleaved e2 transpose
        int k = (s >= 2) ? ((p8 >> 1) | ((p8 & 1) << 4)) : p8;
        int c = half * 16 + (ln & 15);
        float w = fsrc[s][k * 32 + c];
        unsigned short hv = rne_bf16(w);
        if (s == 1) {
            float whi = __builtin_bit_cast(float, (unsigned)hv << 16);
            hv = rne_bf16(w - whi);
        }
        ws16[i * 6144 + s * 1024 + e10] = hv;
    }

    if (tid < 32) {
        int p = tid >> 4, r = tid & 15;
        const float* W   = (p ? sW : tW) + i * 128;
        const float* b   = (p ? sb : tb) + i * 32;
        const float* lng = (p ? s_ln_g : t_ln_g) + i * 32;
        const float* lnb = (p ? s_ln_b : t_ln_b) + i * 32;
        const float* gb  = (p ? s_gb : t_gb) + i * 32;
        const float* bb  = (p ? s_bb : t_bb) + i * 32;
        const float* ow  = (p ? soW : toW) + i * 128;
        float sc = p ? (2.0f * LOG2E) : 1.0f;   // fold tanh's exp2 arg into s-path
        int cL = r, cH = r + 16;
        float* dst = wsP + i * 640 + p * 320;
        f4 v0 = {W[ka*32+cL]*lng[cL], W[(ka+1)*32+cL]*lng[cL], b[cL]*lng[cL], lng[cL]};
        f4 v1 = {W[ka*32+cH]*lng[cH], W[(ka+1)*32+cH]*lng[cH], b[cH]*lng[cH], lng[cH]};
        f4 v2 = {lnb[cL], lnb[cH], gb[cL], gb[cH]};
        f4 v3 = {bb[cL], bb[cH], ow[cL*4+pa]*sc, ow[cL*4+pa+1]*sc};
        f4 v4 = {ow[cH*4+pa]*sc, ow[cH*4+pa+1]*sc, embb2[i*32+cL], embb2[i*32+cH]};
        *(f4*)(dst + 0*64 + r*4) = v0;
        *(f4*)(dst + 1*64 + r*4) = v1;
        *(f4*)(dst + 2*64 + r*4) = v2;
        *(f4*)(dst + 3*64 + r*4) = v3;
        *(f4*)(dst + 4*64 + r*4) = v4;
    } else if (tid < 34) {
        int p = tid - 32;
        const float* W  = (p ? sW : tW) + i * 128;
        const float* b  = (p ? sb : tb) + i * 32;
        const float* ob = (p ? sob : tob) + i * 4;
        float sc = p ? (2.0f * LOG2E) : 1.0f;
        float S0=0,S1=0,Sb=0,Q00=0,Q11=0,Qbb=0,Q01=0,Q0b=0,Q1b=0;
        for (int c = 0; c < 32; ++c) {
            float w0 = W[ka*32+c], w1 = W[(ka+1)*32+c], bc = b[c];
            S0+=w0; S1+=w1; Sb+=bc;
            Q00+=w0*w0; Q11+=w1*w1; Qbb+=bc*bc;
            Q01+=w0*w1; Q0b+=w0*bc; Q1b+=w1*bc;
        }
        const float inv32 = 1.0f / 32.0f;
        float* u = wsU + (i*2+p)*12;
        u[0]=S0*inv32; u[1]=S1*inv32; u[2]=Sb*inv32;
        u[3]=Q00*inv32; u[4]=2.0f*Q01*inv32; u[5]=2.0f*Q0b*inv32;
        u[6]=Q11*inv32; u[7]=2.0f*Q1b*inv32; u[8]=Qbb*inv32;
        u[9]=ob[pa]*sc*(1.0f/16.0f); u[10]=ob[pa+1]*sc*(1.0f/16.0f);
        u[11]=0.0f;
    }
}

// ---------------- one FiLM path on matrix cores ----------------
__device__ __forceinline__ void film_path(
    const unsigned short* __restrict__ fb, int slotg, int slotb, int lane,
    const bf16x8 a2[2], const f4 pv[5], const float* __restrict__ u,
    const f2 (&zk)[2][4], float (&f0)[2][4], float (&f1)[2][4])
{
    bf16x8 gh0 = *(const bf16x8*)(fb + slotg * 1024 + lane * 8);
    bf16x8 gh1 = *(const bf16x8*)(fb + slotg * 1024 + 512 + lane * 8);
    bf16x8 bh0 = *(const bf16x8*)(fb + slotb * 1024 + lane * 8);
    bf16x8 bh1 = *(const bf16x8*)(fb + slotb * 1024 + 512 + lane * 8);
    float gbL = pv[2][2], gbH = pv[2][3], bbL = pv[3][0], bbH = pv[3][1];
    f4 cg0 = {gbL, gbL, gbL, gbL}, cg1 = {gbH, gbH, gbH, gbH};
    f4 cb0 = {bbL, bbL, bbL, bbL}, cb1 = {bbH, bbH, bbH, bbH};
    f4 gacc[2][2], bacc[2][2];
    #pragma unroll
    for (int t = 0; t < 2; ++t) {
        gacc[t][0] = __builtin_amdgcn_mfma_f32_16x16x32_bf16(a2[t], gh0, cg0, 0, 0, 0);
        gacc[t][1] = __builtin_amdgcn_mfma_f32_16x16x32_bf16(a2[t], gh1, cg1, 0, 0, 0);
        bacc[t][0] = __builtin_amdgcn_mfma_f32_16x16x32_bf16(a2[t], bh0, cb0, 0, 0, 0);
        bacc[t][1] = __builtin_amdgcn_mfma_f32_16x16x32_bf16(a2[t], bh1, cb1, 0, 0, 0);
    }
    float S0=u[0], S1=u[1], Sb=u[2], Q00=u[3], Q01=u[4], Q0b=u[5];
    float Q11=u[6], Q1b=u[7], Qbb=u[8], ob0=u[9], ob1=u[10];
    float wk0L=pv[0][0], wk1L=pv[0][1], bL=pv[0][2], lngL=pv[0][3];
    float wk0H=pv[1][0], wk1H=pv[1][1], bH=pv[1][2], lngH=pv[1][3];
    float lnbL=pv[2][0], lnbH=pv[2][1];
    float owL0=pv[3][2], owL1=pv[3][3], owH0=pv[4][0], owH1=pv[4][1];
    #pragma unroll
    for (int t = 0; t < 2; ++t) {
        #pragma unroll
        for (int q = 0; q < 4; ++q) {
            float za = zk[t][q][0], zb = zk[t][q][1];
            float m = fmaf(za, S0, fmaf(zb, S1, Sb));
            float ex2 = fmaf(za, fmaf(za, Q00, fmaf(zb, Q01, Q0b)),
                             fmaf(zb, fmaf(zb, Q11, Q1b), Qbb));
            float var = fmaxf(fmaf(-m, m, ex2), 0.0f);
            float rstd = __builtin_amdgcn_rsqf(var + LN_EPS);
            float mr = m * rstd;
            float hL = fmaf(za, wk0L, fmaf(zb, wk1L, bL));
            float hH = fmaf(za, wk0H, fmaf(zb, wk1H, bH));
            float nL = fmaf(hL, rstd, fmaf(-mr, lngL, lnbL));
            float nH = fmaf(hH, rstd, fmaf(-mr, lngH, lnbH));
            float gL = gacc[t][0][q], gH = gacc[t][1][q];
            float btL = bacc[t][0][q], btH = bacc[t][1][q];
            float thL = fmaxf(fmaf(gL, nL, nL + btL), 0.0f);
            float thH = fmaxf(fmaf(gH, nH, nH + btH), 0.0f);
            float p0 = fmaf(thL, owL0, fmaf(thH, owH0, ob0));
            float p1 = fmaf(thL, owL1, fmaf(thH, owH1, ob1));
            f0[t][q] = reduce16(p0);
            f1[t][q] = reduce16(p1);
        }
    }
}

__device__ __forceinline__ void layer_body(
    int i, const unsigned short* __restrict__ ws16,
    const float* __restrict__ wsP, const float* __restrict__ wsU,
    const float* __restrict__ embW1, const float* __restrict__ embb1,
    int lane, int r, int g, unsigned char* T, const f4 y4[2],
    f2 (&zk)[2][4], f2 (&zt)[2][4], f4& ld0, f4& ld1)
{
    const unsigned short* fb = ws16 + i * 6144;
    const float* pP = wsP + i * 640;
    const float* uT = wsU + (i * 2) * 12;
    const float* uS = uT + 12;

    f4 ptv[5];
    #pragma unroll
    for (int v = 0; v < 5; ++v) ptv[v] = *(const f4*)(pP + v * 64 + r * 4);

    // ---- e1 = relu(y @ W1 + b1) directly in A-fragment layout ----
    const float* W1 = embW1 + i * 128;
    f4 w1a[4], w1b[4];
    #pragma unroll
    for (int c = 0; c < 4; ++c) {
        w1a[c] = *(const f4*)(W1 + c * 32 + g * 8);
        w1b[c] = *(const f4*)(W1 + c * 32 + g * 8 + 4);
    }
    f4 b1a = *(const f4*)(embb1 + i * 32 + g * 8);
    f4 b1b = *(const f4*)(embb1 + i * 32 + g * 8 + 4);
    bf16x8 a1[2];
    #pragma unroll
    for (int t = 0; t < 2; ++t) {
        unsigned aw[4];
        #pragma unroll
        for (int jp = 0; jp < 4; ++jp) {
            const int j0 = 2 * jp, j1 = 2 * jp + 1;
            float aL = (j0 < 4) ? b1a[j0 & 3] : b1b[j0 & 3];
            float aH = (j1 < 4) ? b1a[j1 & 3] : b1b[j1 & 3];
            #pragma unroll
            for (int c = 0; c < 4; ++c) {
                aL = fmaf(y4[t][c], (j0 < 4) ? w1a[c][j0 & 3] : w1b[c][j0 & 3], aL);
                aH = fmaf(y4[t][c], (j1 < 4) ? w1a[c][j1 & 3] : w1b[c][j1 & 3], aH);
            }
            aw[jp] = cvt_pk_bf16(fmaxf(aL, 0.0f), fmaxf(aH, 0.0f));
        }
        i4 ai = {(int)aw[0], (int)aw[1], (int)aw[2], (int)aw[3]};
        a1[t] = __builtin_bit_cast(bf16x8, ai);
    }

    // ---- e2 = relu(e1 @ W2 + b2) via MFMA (hi+lo weights, bias in C) ----
    bf16x8 w2h0 = *(const bf16x8*)(fb + lane * 8);
    bf16x8 w2h1 = *(const bf16x8*)(fb + 512 + lane * 8);
    bf16x8 w2l0 = *(const bf16x8*)(fb + 1024 + lane * 8);
    bf16x8 w2l1 = *(const bf16x8*)(fb + 1536 + lane * 8);
    float b2L = ptv[4][2], b2H = ptv[4][3];
    f4 c2L = {b2L, b2L, b2L, b2L}, c2H = {b2H, b2H, b2H, b2H};
    f4 e2a[2][2];
    #pragma unroll
    for (int t = 0; t < 2; ++t) {
        e2a[t][0] = __builtin_amdgcn_mfma_f32_16x16x32_bf16(a1[t], w2h0, c2L, 0, 0, 0);
        e2a[t][0] = __builtin_amdgcn_mfma_f32_16x16x32_bf16(a1[t], w2l0, e2a[t][0], 0, 0, 0);
        e2a[t][1] = __builtin_amdgcn_mfma_f32_16x16x32_bf16(a1[t], w2h1, c2H, 0, 0, 0);
        e2a[t][1] = __builtin_amdgcn_mfma_f32_16x16x32_bf16(a1[t], w2l1, e2a[t][1], 0, 0, 0);
    }

    // ---- D-layout -> A-layout transpose through LDS (k-interleaved pack) ----
    #pragma unroll
    for (int t = 0; t < 2; ++t)
        #pragma unroll
        for (int q = 0; q < 4; ++q) {
            int rowl = 16 * t + 4 * g + q;
            float vl = fmaxf(e2a[t][0][q], 0.0f);
            float vh = fmaxf(e2a[t][1][q], 0.0f);
            *(unsigned*)(T + rowl * 80 + r * 4) = cvt_pk_bf16(vl, vh);
        }
    asm volatile("s_waitcnt lgkmcnt(0)" ::: "memory");
    __builtin_amdgcn_sched_barrier(0);
    bf16x8 a2[2];
    a2[0] = *(const bf16x8*)(T + r * 80 + g * 16);
    a2[1] = *(const bf16x8*)(T + (16 + r) * 80 + g * 16);

    // ---- t and s FiLM paths ----
    float tf0[2][4], tf1[2][4], sf0[2][4], sf1[2][4];
    film_path(fb, 2, 3, lane, a2, ptv, uT, zk, tf0, tf1);
    f4 psv[5];
    #pragma unroll
    for (int v = 0; v < 5; ++v) psv[v] = *(const f4*)(pP + 320 + v * 64 + r * 4);
    film_path(fb, 4, 5, lane, a2, psv, uS, zk, sf0, sf1);

    // ---- coupling update: sf already scaled by 2*log2e; tanh = 1 - 2/(exp2(x)+1) ----
    // No clamp needed: exp2(+inf)->inf -> rcp->0 -> s=1; exp2(-inf)->0 -> rcp(1)=1 -> s=-1.
    #pragma unroll
    for (int t = 0; t < 2; ++t)
        #pragma unroll
        for (int q = 0; q < 4; ++q) {
            float x0 = sf0[t][q];
            float x1 = sf1[t][q];
            float e0 = __builtin_amdgcn_exp2f(x0);
            float e1_ = __builtin_amdgcn_exp2f(x1);
            float r0 = __builtin_amdgcn_rcpf(e0 + 1.0f);
            float r1 = __builtin_amdgcn_rcpf(e1_ + 1.0f);
            float s0 = fmaf(-2.0f, r0, 1.0f);
            float s1 = fmaf(-2.0f, r1, 1.0f);
            float eA = __builtin_amdgcn_exp2f(s0 * LOG2E);
            float eB = __builtin_amdgcn_exp2f(s1 * LOG2E);
            zt[t][q][0] = fmaf(zt[t][q][0], eA, tf0[t][q]);
            zt[t][q][1] = fmaf(zt[t][q][1], eB, tf1[t][q]);
            if (t == 0) ld0[q] += s0 + s1; else ld1[q] += s0 + s1;
        }
}

__global__ __launch_bounds__(256, 1) void realnvp_mfma(
    const float* __restrict__ x, const float* __restrict__ y,
    const float* __restrict__ embW1, const float* __restrict__ embb1,
    const unsigned short* __restrict__ ws16,
    const float* __restrict__ wsP, const float* __restrict__ wsU,
    float* __restrict__ out_z, float* __restrict__ out_ld)
{
    __shared__ __align__(16) unsigned char ldsbuf[4 * 2560];
    const int lane = threadIdx.x & 63;
    const int wv = threadIdx.x >> 6;
    const int r = lane & 15, g = lane >> 4;
    unsigned char* T = ldsbuf + wv * 2560;   // 32 rows x 80B pitch
    const int row0 = (blockIdx.x * 4 + wv) * 32;

    // zA = dims(0,1), zB = dims(2,3); rows replicated across the 16-lane group
    f2 zA[2][4], zB[2][4];
    #pragma unroll
    for (int t = 0; t < 2; ++t)
        #pragma unroll
        for (int q = 0; q < 4; ++q) {
            f4 xv = *(const f4*)(x + (size_t)(row0 + 16 * t + 4 * g + q) * 4);
            zA[t][q][0] = xv.x; zA[t][q][1] = xv.y;
            zB[t][q][0] = xv.z; zB[t][q][1] = xv.w;
        }
    f4 y4[2];
    #pragma unroll
    for (int t = 0; t < 2; ++t)
        y4[t] = *(const f4*)(y + (size_t)(row0 + 16 * t + r) * 4);
    f4 ld0 = {0.f, 0.f, 0.f, 0.f}, ld1 = {0.f, 0.f, 0.f, 0.f};

    #pragma unroll 1
    for (int ii = 0; ii < 4; ++ii) {
        layer_body(2 * ii,     ws16, wsP, wsU, embW1, embb1, lane, r, g, T, y4, zA, zB, ld0, ld1);
        layer_body(2 * ii + 1, ws16, wsP, wsU, embW1, embb1, lane, r, g, T, y4, zB, zA, ld0, ld1);
    }

    if (r == 0) {
        #pragma unroll
        for (int t = 0; t < 2; ++t)
            #pragma unroll
            for (int q = 0; q < 4; ++q) {
                f4 zo = {zA[t][q][0], zA[t][q][1], zB[t][q][0], zB[t][q][1]};
                *(f4*)(out_z + (size_t)(row0 + 16 * t + 4 * g + q) * 4) = zo;
            }
        *(f4*)(out_ld + row0 + 4 * g) = ld0;
        *(f4*)(out_ld + row0 + 16 + 4 * g) = ld1;
    }
}

extern "C" void kernel_launch(void* const* d_in, const int* in_sizes, int n_in,
                              void* d_out, int out_size, void* d_ws, size_t ws_size,
                              hipStream_t stream) {
    const float* x      = (const float*)d_in[0];
    const float* y      = (const float*)d_in[1];
    const float* embW1  = (const float*)d_in[2];
    const float* embb1  = (const float*)d_in[3];
    const float* embW2  = (const float*)d_in[4];
    const float* embb2  = (const float*)d_in[5];
    const float* tW     = (const float*)d_in[6];
    const float* tb     = (const float*)d_in[7];
    const float* t_ln_g = (const float*)d_in[8];
    const float* t_ln_b = (const float*)d_in[9];
    const float* t_gW   = (const float*)d_in[10];
    const float* t_gb   = (const float*)d_in[11];
    const float* t_bW   = (const float*)d_in[12];
    const float* t_bb   = (const float*)d_in[13];
    const float* toW    = (const float*)d_in[14];
    const float* tob    = (const float*)d_in[15];
    const float* sW     = (const float*)d_in[16];
    const float* sb     = (const float*)d_in[17];
    const float* s_ln_g = (const float*)d_in[18];
    const float* s_ln_b = (const float*)d_in[19];
    const float* s_gW   = (const float*)d_in[20];
    const float* s_gb   = (const float*)d_in[21];
    const float* s_bW   = (const float*)d_in[22];
    const float* s_bb   = (const float*)d_in[23];
    const float* soW    = (const float*)d_in[24];
    const float* sob    = (const float*)d_in[25];

    if (ws_size < WS_NEED) return;
    unsigned short* ws16 = (unsigned short*)d_ws;
    float* wsP = (float*)((char*)d_ws + WS_PARM_OFF);
    float* wsU = (float*)((char*)d_ws + WS_UNIF_OFF);

    int B = in_sizes[0] / 4;
    float* out_z  = (float*)d_out;
    float* out_ld = out_z + (size_t)B * 4;

    hipLaunchKernelGGL(preproc_kernel, dim3(8), dim3(256), 0, stream,
                       embW2, embb2, tW, tb, t_ln_g, t_ln_b, t_gW, t_gb,
                       t_bW, t_bb, toW, tob, sW, sb, s_ln_g, s_ln_b,
                       s_gW, s_gb, s_bW, s_bb, soW, sob, ws16, wsP, wsU);
    hipLaunchKernelGGL(realnvp_mfma, dim3(B / 128), dim3(256), 0, stream,
                       x, y, embW1, embb1, ws16, wsP, wsU, out_z, out_ld);
}

// Round 10
// 119.327 us; speedup vs baseline: 21.2727x; 1.1669x over previous
//
#include <hip/hip_runtime.h>
#include <math.h>

#define LN_EPS 1e-5f
#define LOG2E 1.44269504088896f
#define LN2   0.69314718055994531f

typedef float f4 __attribute__((ext_vector_type(4)));
typedef float f2 __attribute__((ext_vector_type(2)));
typedef int   i4 __attribute__((ext_vector_type(4)));
typedef short bf16x8 __attribute__((ext_vector_type(8)));

// d_ws layout (bytes):
//   [0, 98304)        frags: [layer8][slot6][half2][lane64][j8] bf16
//                     slots: 0=W2hi 1=W2lo 2=tG 3=tB 4=sG 5=sB
//   [98304, 139264)   params: [layer8][path2][vec5][r16][4] f32
//   [139264, 140032)  uniforms: [layer8][path2][12] f32
#define WS_PARM_OFF 98304
#define WS_UNIF_OFF 139264
#define WS_NEED 140032

#define WAITLGKM() do { \
    asm volatile("s_waitcnt lgkmcnt(0)" ::: "memory"); \
    __builtin_amdgcn_sched_barrier(0); \
} while (0)

__device__ __forceinline__ unsigned short rne_bf16(float f) {
    unsigned u = __builtin_bit_cast(unsigned, f);
    unsigned r = (u + 0x7FFFu + ((u >> 16) & 1u)) >> 16;
    return (unsigned short)r;
}

// packed f32->bf16 convert (RNE), one VALU op for two conversions
__device__ __forceinline__ unsigned cvt_pk_bf16(float lo, float hi) {
    unsigned r;
    asm("v_cvt_pk_bf16_f32 %0, %1, %2" : "=v"(r) : "v"(lo), "v"(hi));
    return r;
}

template <int CTRL>
__device__ __forceinline__ float dpp_add_step(float v) {
    int t = __builtin_amdgcn_update_dpp(0, __builtin_bit_cast(int, v), CTRL, 0xf, 0xf, true);
    return v + __builtin_bit_cast(float, t);
}
// sum across the 16-lane DPP row; result identical in all 16 lanes
__device__ __forceinline__ float reduce16(float v) {
    v = dpp_add_step<0xB1>(v);   // quad_perm(1,0,3,2)
    v = dpp_add_step<0x4E>(v);   // quad_perm(2,3,0,1)
    v = dpp_add_step<0x141>(v);  // row_half_mirror
    v = dpp_add_step<0x140>(v);  // row_mirror
    return v;
}

// ---------------- preprocessing (identical to round 9) ----------------
__global__ void preproc_kernel(
    const float* __restrict__ embW2, const float* __restrict__ embb2,
    const float* __restrict__ tW, const float* __restrict__ tb,
    const float* __restrict__ t_ln_g, const float* __restrict__ t_ln_b,
    const float* __restrict__ t_gW, const float* __restrict__ t_gb,
    const float* __restrict__ t_bW, const float* __restrict__ t_bb,
    const float* __restrict__ toW, const float* __restrict__ tob,
    const float* __restrict__ sW, const float* __restrict__ sb,
    const float* __restrict__ s_ln_g, const float* __restrict__ s_ln_b,
    const float* __restrict__ s_gW, const float* __restrict__ s_gb,
    const float* __restrict__ s_bW, const float* __restrict__ s_bb,
    const float* __restrict__ soW, const float* __restrict__ sob,
    unsigned short* __restrict__ ws16, float* __restrict__ wsP,
    float* __restrict__ wsU)
{
    const int i = blockIdx.x;
    const int tid = threadIdx.x;
    const int parity = i & 1;
    const int ka = parity ? 2 : 0, pa = parity ? 0 : 2;

    const float* fsrc[6] = {embW2 + i * 1024, embW2 + i * 1024,
                            t_gW + i * 1024, t_bW + i * 1024,
                            s_gW + i * 1024, s_bW + i * 1024};
    for (int e = tid; e < 6144; e += 256) {
        int s = e >> 10, e10 = e & 1023;
        int half = e10 >> 9, ln = (e10 >> 3) & 63, j = e10 & 7;
        int p8 = (ln >> 4) * 8 + j;
        int k = (s >= 2) ? ((p8 >> 1) | ((p8 & 1) << 4)) : p8;
        int c = half * 16 + (ln & 15);
        float w = fsrc[s][k * 32 + c];
        unsigned short hv = rne_bf16(w);
        if (s == 1) {
            float whi = __builtin_bit_cast(float, (unsigned)hv << 16);
            hv = rne_bf16(w - whi);
        }
        ws16[i * 6144 + s * 1024 + e10] = hv;
    }

    if (tid < 32) {
        int p = tid >> 4, r = tid & 15;
        const float* W   = (p ? sW : tW) + i * 128;
        const float* b   = (p ? sb : tb) + i * 32;
        const float* lng = (p ? s_ln_g : t_ln_g) + i * 32;
        const float* lnb = (p ? s_ln_b : t_ln_b) + i * 32;
        const float* gb  = (p ? s_gb : t_gb) + i * 32;
        const float* bb  = (p ? s_bb : t_bb) + i * 32;
        const float* ow  = (p ? soW : toW) + i * 128;
        float sc = p ? (2.0f * LOG2E) : 1.0f;
        int cL = r, cH = r + 16;
        float* dst = wsP + i * 640 + p * 320;
        f4 v0 = {W[ka*32+cL]*lng[cL], W[(ka+1)*32+cL]*lng[cL], b[cL]*lng[cL], lng[cL]};
        f4 v1 = {W[ka*32+cH]*lng[cH], W[(ka+1)*32+cH]*lng[cH], b[cH]*lng[cH], lng[cH]};
        f4 v2 = {lnb[cL], lnb[cH], gb[cL], gb[cH]};
        f4 v3 = {bb[cL], bb[cH], ow[cL*4+pa]*sc, ow[cL*4+pa+1]*sc};
        f4 v4 = {ow[cH*4+pa]*sc, ow[cH*4+pa+1]*sc, embb2[i*32+cL], embb2[i*32+cH]};
        *(f4*)(dst + 0*64 + r*4) = v0;
        *(f4*)(dst + 1*64 + r*4) = v1;
        *(f4*)(dst + 2*64 + r*4) = v2;
        *(f4*)(dst + 3*64 + r*4) = v3;
        *(f4*)(dst + 4*64 + r*4) = v4;
    } else if (tid < 34) {
        int p = tid - 32;
        const float* W  = (p ? sW : tW) + i * 128;
        const float* b  = (p ? sb : tb) + i * 32;
        const float* ob = (p ? sob : tob) + i * 4;
        float sc = p ? (2.0f * LOG2E) : 1.0f;
        float S0=0,S1=0,Sb=0,Q00=0,Q11=0,Qbb=0,Q01=0,Q0b=0,Q1b=0;
        for (int c = 0; c < 32; ++c) {
            float w0 = W[ka*32+c], w1 = W[(ka+1)*32+c], bc = b[c];
            S0+=w0; S1+=w1; Sb+=bc;
            Q00+=w0*w0; Q11+=w1*w1; Qbb+=bc*bc;
            Q01+=w0*w1; Q0b+=w0*bc; Q1b+=w1*bc;
        }
        const float inv32 = 1.0f / 32.0f;
        float* u = wsU + (i*2+p)*12;
        u[0]=S0*inv32; u[1]=S1*inv32; u[2]=Sb*inv32;
        u[3]=Q00*inv32; u[4]=2.0f*Q01*inv32; u[5]=2.0f*Q0b*inv32;
        u[6]=Q11*inv32; u[7]=2.0f*Q1b*inv32; u[8]=Qbb*inv32;
        u[9]=ob[pa]*sc*(1.0f/16.0f); u[10]=ob[pa+1]*sc*(1.0f/16.0f);
        u[11]=0.0f;
    }
}

// ---------------- one FiLM path; z and LN stats read from LDS ----------------
__device__ __forceinline__ void film_path(
    const unsigned short* __restrict__ fb, int slotg, int slotb, int lane,
    int kaf, int path, const float* Z, const float* ST,
    const bf16x8 a2[2], const f4 pv[5], const float* __restrict__ u,
    float (&f0)[2][4], float (&f1)[2][4])
{
    const int g = lane >> 4;
    bf16x8 gh0 = *(const bf16x8*)(fb + slotg * 1024 + lane * 8);
    bf16x8 gh1 = *(const bf16x8*)(fb + slotg * 1024 + 512 + lane * 8);
    bf16x8 bh0 = *(const bf16x8*)(fb + slotb * 1024 + lane * 8);
    bf16x8 bh1 = *(const bf16x8*)(fb + slotb * 1024 + 512 + lane * 8);
    float gbL = pv[2][2], gbH = pv[2][3], bbL = pv[3][0], bbH = pv[3][1];
    f4 cg0 = {gbL, gbL, gbL, gbL}, cg1 = {gbH, gbH, gbH, gbH};
    f4 cb0 = {bbL, bbL, bbL, bbL}, cb1 = {bbH, bbH, bbH, bbH};
    f4 gacc[2][2], bacc[2][2];
    #pragma unroll
    for (int t = 0; t < 2; ++t) {
        gacc[t][0] = __builtin_amdgcn_mfma_f32_16x16x32_bf16(a2[t], gh0, cg0, 0, 0, 0);
        gacc[t][1] = __builtin_amdgcn_mfma_f32_16x16x32_bf16(a2[t], gh1, cg1, 0, 0, 0);
        bacc[t][0] = __builtin_amdgcn_mfma_f32_16x16x32_bf16(a2[t], bh0, cb0, 0, 0, 0);
        bacc[t][1] = __builtin_amdgcn_mfma_f32_16x16x32_bf16(a2[t], bh1, cb1, 0, 0, 0);
    }
    float ob0 = u[9], ob1 = u[10];
    float wk0L=pv[0][0], wk1L=pv[0][1], bL=pv[0][2], lngL=pv[0][3];
    float wk0H=pv[1][0], wk1H=pv[1][1], bH=pv[1][2], lngH=pv[1][3];
    float lnbL=pv[2][0], lnbH=pv[2][1];
    float owL0=pv[3][2], owL1=pv[3][3], owH0=pv[4][0], owH1=pv[4][1];
    #pragma unroll
    for (int t = 0; t < 2; ++t) {
        #pragma unroll
        for (int q = 0; q < 4; ++q) {
            int rowl = 16 * t + 4 * g + q;
            f2 zkv = *(const f2*)(Z + rowl * 4 + kaf);     // broadcast read
            f2 st  = *(const f2*)(ST + rowl * 4 + path * 2); // {-m*rstd, rstd}
            float hL = fmaf(zkv[0], wk0L, fmaf(zkv[1], wk1L, bL));
            float hH = fmaf(zkv[0], wk0H, fmaf(zkv[1], wk1H, bH));
            float nL = fmaf(hL, st[1], fmaf(st[0], lngL, lnbL));
            float nH = fmaf(hH, st[1], fmaf(st[0], lngH, lnbH));
            float gL = gacc[t][0][q], gH = gacc[t][1][q];
            float btL = bacc[t][0][q], btH = bacc[t][1][q];
            float thL = fmaxf(fmaf(gL, nL, nL + btL), 0.0f);
            float thH = fmaxf(fmaf(gH, nH, nH + btH), 0.0f);
            float p0 = fmaf(thL, owL0, fmaf(thH, owH0, ob0));
            float p1 = fmaf(thL, owL1, fmaf(thH, owH1, ob1));
            f0[t][q] = reduce16(p0);
            f1[t][q] = reduce16(p1);
        }
    }
}

__global__ __launch_bounds__(256, 1) void realnvp_mfma(
    const float* __restrict__ x, const float* __restrict__ y,
    const float* __restrict__ embW1, const float* __restrict__ embb1,
    const unsigned short* __restrict__ ws16,
    const float* __restrict__ wsP, const float* __restrict__ wsU,
    float* __restrict__ out_z, float* __restrict__ out_ld)
{
    __shared__ __align__(16) unsigned char ldsbuf[4 * 4096];
    const int lane = threadIdx.x & 63;
    const int wv = threadIdx.x >> 6;
    const int r = lane & 15, g = lane >> 4;
    const int rs = lane & 31, hw = lane >> 5;
    unsigned char* T = ldsbuf + wv * 4096;           // 32 rows x 80B (e2 transpose)
    float* Z  = (float*)(ldsbuf + wv * 4096 + 2560); // 32 x f4 (z rows)
    float* ST = (float*)(ldsbuf + wv * 4096 + 3072); // 32 x {-mrT,rstdT,-mrS,rstdS}
    float* FB = (float*)(ldsbuf + wv * 4096 + 3584); // 32 x {tf0,sf0,tf1,sf1}
    const int row0 = (blockIdx.x * 4 + wv) * 32;

    if (lane < 32) {
        *(f4*)(Z + rs * 4) = *(const f4*)(x + (size_t)(row0 + rs) * 4);
    }
    f4 y4[2];
    y4[0] = *(const f4*)(y + (size_t)(row0 + r) * 4);
    y4[1] = *(const f4*)(y + (size_t)(row0 + 16 + r) * 4);
    float ld2 = 0.0f;
    WAITLGKM();

    #pragma unroll 1
    for (int i = 0; i < 8; ++i) {
        const int parity = i & 1;
        const int kaf = parity ? 2 : 0;   // kept-dim offset in z row
        const int pa  = parity ? 0 : 2;   // transform-dim base
        const unsigned short* fb = ws16 + i * 6144;
        const float* pP = wsP + i * 640;
        const float* uT = wsU + (i * 2) * 12;
        const float* uS = uT + 12;

        // ---- LN stats: row-per-lane, paths split across half-waves ----
        {
            f2 zk = *(const f2*)(Z + rs * 4 + kaf);
            const float* ub = wsU + (i * 2 + hw) * 12;
            f4 u0 = *(const f4*)(ub);        // {S0,S1,Sb,Q00}
            f4 u1 = *(const f4*)(ub + 4);    // {Q01,Q0b,Q11,Q1b}
            f4 u2 = *(const f4*)(ub + 8);    // {Qbb,obc0,obc1,0}
            float za = zk[0], zb = zk[1];
            float m   = fmaf(za, u0[0], fmaf(zb, u0[1], u0[2]));
            float ex2 = fmaf(za, fmaf(za, u0[3], fmaf(zb, u1[0], u1[1])),
                             fmaf(zb, fmaf(zb, u1[2], u1[3]), u2[0]));
            float var = fmaxf(fmaf(-m, m, ex2), 0.0f);
            float rstd = __builtin_amdgcn_rsqf(var + LN_EPS);
            f2 stv = {-m * rstd, rstd};
            *(f2*)(ST + rs * 4 + hw * 2) = stv;
        }

        f4 ptv[5];
        #pragma unroll
        for (int v = 0; v < 5; ++v) ptv[v] = *(const f4*)(pP + v * 64 + r * 4);

        // ---- e1 = relu(y @ W1 + b1) directly in A-fragment layout ----
        const float* W1 = embW1 + i * 128;
        f4 w1a[4], w1b[4];
        #pragma unroll
        for (int c = 0; c < 4; ++c) {
            w1a[c] = *(const f4*)(W1 + c * 32 + g * 8);
            w1b[c] = *(const f4*)(W1 + c * 32 + g * 8 + 4);
        }
        f4 b1a = *(const f4*)(embb1 + i * 32 + g * 8);
        f4 b1b = *(const f4*)(embb1 + i * 32 + g * 8 + 4);
        bf16x8 a1[2];
        #pragma unroll
        for (int t = 0; t < 2; ++t) {
            unsigned aw[4];
            #pragma unroll
            for (int jp = 0; jp < 4; ++jp) {
                const int j0 = 2 * jp, j1 = 2 * jp + 1;
                float aL = (j0 < 4) ? b1a[j0 & 3] : b1b[j0 & 3];
                float aH = (j1 < 4) ? b1a[j1 & 3] : b1b[j1 & 3];
                #pragma unroll
                for (int c = 0; c < 4; ++c) {
                    aL = fmaf(y4[t][c], (j0 < 4) ? w1a[c][j0 & 3] : w1b[c][j0 & 3], aL);
                    aH = fmaf(y4[t][c], (j1 < 4) ? w1a[c][j1 & 3] : w1b[c][j1 & 3], aH);
                }
                aw[jp] = cvt_pk_bf16(fmaxf(aL, 0.0f), fmaxf(aH, 0.0f));
            }
            i4 ai = {(int)aw[0], (int)aw[1], (int)aw[2], (int)aw[3]};
            a1[t] = __builtin_bit_cast(bf16x8, ai);
        }

        // ---- e2 = relu(e1 @ W2 + b2) via MFMA (hi+lo weights, bias in C) ----
        bf16x8 w2h0 = *(const bf16x8*)(fb + lane * 8);
        bf16x8 w2h1 = *(const bf16x8*)(fb + 512 + lane * 8);
        bf16x8 w2l0 = *(const bf16x8*)(fb + 1024 + lane * 8);
        bf16x8 w2l1 = *(const bf16x8*)(fb + 1536 + lane * 8);
        float b2L = ptv[4][2], b2H = ptv[4][3];
        f4 c2L = {b2L, b2L, b2L, b2L}, c2H = {b2H, b2H, b2H, b2H};
        f4 e2a[2][2];
        #pragma unroll
        for (int t = 0; t < 2; ++t) {
            e2a[t][0] = __builtin_amdgcn_mfma_f32_16x16x32_bf16(a1[t], w2h0, c2L, 0, 0, 0);
            e2a[t][0] = __builtin_amdgcn_mfma_f32_16x16x32_bf16(a1[t], w2l0, e2a[t][0], 0, 0, 0);
            e2a[t][1] = __builtin_amdgcn_mfma_f32_16x16x32_bf16(a1[t], w2h1, c2H, 0, 0, 0);
            e2a[t][1] = __builtin_amdgcn_mfma_f32_16x16x32_bf16(a1[t], w2l1, e2a[t][1], 0, 0, 0);
        }

        // ---- D-layout -> A-layout transpose through LDS ----
        #pragma unroll
        for (int t = 0; t < 2; ++t)
            #pragma unroll
            for (int q = 0; q < 4; ++q) {
                int rowl = 16 * t + 4 * g + q;
                float vl = fmaxf(e2a[t][0][q], 0.0f);
                float vh = fmaxf(e2a[t][1][q], 0.0f);
                *(unsigned*)(T + rowl * 80 + r * 4) = cvt_pk_bf16(vl, vh);
            }
        WAITLGKM();   // drains T pack AND the ST stat write above
        bf16x8 a2[2];
        a2[0] = *(const bf16x8*)(T + r * 80 + g * 16);
        a2[1] = *(const bf16x8*)(T + (16 + r) * 80 + g * 16);

        // ---- t and s FiLM paths (z, stats from LDS) ----
        float tf0[2][4], tf1[2][4], sf0[2][4], sf1[2][4];
        film_path(fb, 2, 3, lane, kaf, 0, Z, ST, a2, ptv, uT, tf0, tf1);
        f4 psv[5];
        #pragma unroll
        for (int v = 0; v < 5; ++v) psv[v] = *(const f4*)(pP + 320 + v * 64 + r * 4);
        film_path(fb, 4, 5, lane, kaf, 1, Z, ST, a2, psv, uS, sf0, sf1);

        // ---- publish per-row results (one writer lane per group) ----
        if (r == 0) {
            #pragma unroll
            for (int t = 0; t < 2; ++t)
                #pragma unroll
                for (int q = 0; q < 4; ++q) {
                    int rowl = 16 * t + 4 * g + q;
                    f4 v = {tf0[t][q], sf0[t][q], tf1[t][q], sf1[t][q]};
                    *(f4*)(FB + rowl * 4) = v;
                }
        }
        WAITLGKM();

        // ---- coupling tail: row-per-lane, dims split across half-waves ----
        {
            int d = pa + hw;
            f2 fv = *(const f2*)(FB + rs * 4 + hw * 2);   // {tf_d, sf_d}
            float e  = __builtin_amdgcn_exp2f(fv[1]);     // sf pre-scaled by 2*log2e
            float rc = __builtin_amdgcn_rcpf(e + 1.0f);
            float s2 = fmaf(-2.0f * LOG2E, rc, LOG2E);    // tanh(.)*log2e
            float eA = __builtin_amdgcn_exp2f(s2);
            float zo = Z[rs * 4 + d];
            Z[rs * 4 + d] = fmaf(zo, eA, fv[0]);
            ld2 += s2;
        }
        WAITLGKM();
    }

    float oth = __shfl(ld2, lane ^ 32, 64);
    float ldv = (ld2 + oth) * LN2;
    if (lane < 32) {
        f4 zo = *(const f4*)(Z + rs * 4);
        *(f4*)(out_z + (size_t)(row0 + rs) * 4) = zo;
        out_ld[row0 + rs] = ldv;
    }
}

extern "C" void kernel_launch(void* const* d_in, const int* in_sizes, int n_in,
                              void* d_out, int out_size, void* d_ws, size_t ws_size,
                              hipStream_t stream) {
    const float* x      = (const float*)d_in[0];
    const float* y      = (const float*)d_in[1];
    const float* embW1  = (const float*)d_in[2];
    const float* embb1  = (const float*)d_in[3];
    const float* embW2  = (const float*)d_in[4];
    const float* embb2  = (const float*)d_in[5];
    const float* tW     = (const float*)d_in[6];
    const float* tb     = (const float*)d_in[7];
    const float* t_ln_g = (const float*)d_in[8];
    const float* t_ln_b = (const float*)d_in[9];
    const float* t_gW   = (const float*)d_in[10];
    const float* t_gb   = (const float*)d_in[11];
    const float* t_bW   = (const float*)d_in[12];
    const float* t_bb   = (const float*)d_in[13];
    const float* toW    = (const float*)d_in[14];
    const float* tob    = (const float*)d_in[15];
    const float* sW     = (const float*)d_in[16];
    const float* sb     = (const float*)d_in[17];
    const float* s_ln_g = (const float*)d_in[18];
    const float* s_ln_b = (const float*)d_in[19];
    const float* s_gW   = (const float*)d_in[20];
    const float* s_gb   = (const float*)d_in[21];
    const float* s_bW   = (const float*)d_in[22];
    const float* s_bb   = (const float*)d_in[23];
    const float* soW    = (const float*)d_in[24];
    const float* sob    = (const float*)d_in[25];

    if (ws_size < WS_NEED) return;
    unsigned short* ws16 = (unsigned short*)d_ws;
    float* wsP = (float*)((char*)d_ws + WS_PARM_OFF);
    float* wsU = (float*)((char*)d_ws + WS_UNIF_OFF);

    int B = in_sizes[0] / 4;
    float* out_z  = (float*)d_out;
    float* out_ld = out_z + (size_t)B * 4;

    hipLaunchKernelGGL(preproc_kernel, dim3(8), dim3(256), 0, stream,
                       embW2, embb2, tW, tb, t_ln_g, t_ln_b, t_gW, t_gb,
                       t_bW, t_bb, toW, tob, sW, sb, s_ln_g, s_ln_b,
                       s_gW, s_gb, s_bW, s_bb, soW, sob, ws16, wsP, wsU);
    hipLaunchKernelGGL(realnvp_mfma, dim3(B / 128), dim3(256), 0, stream,
                       x, y, embW1, embb1, ws16, wsP, wsU, out_z, out_ld);
}